// Round 1
// baseline (1011.390 us; speedup 1.0000x reference)
//
#include <hip/hip_runtime.h>

#define BM 256
#define BN 64
#define BK 32
#define BMP (BM + 4)   // padded LDS stride: keeps 16B alignment, breaks 8-way store conflicts

// ---------------- degree ----------------
__global__ void deg_kernel(const int* __restrict__ src, const int* __restrict__ dst,
                           int E, int* __restrict__ outdeg, int* __restrict__ indeg) {
  int stride = gridDim.x * blockDim.x;
  for (int e = blockIdx.x * blockDim.x + threadIdx.x; e < E; e += stride) {
    atomicAdd(&outdeg[src[e]], 1);
    atomicAdd(&indeg[dst[e]], 1);
  }
}

__global__ void norm_kernel(const int* __restrict__ outdeg, const int* __restrict__ indeg,
                            int N, float* __restrict__ out_norm, float* __restrict__ in_norm) {
  int i = blockIdx.x * blockDim.x + threadIdx.x;
  if (i >= N) return;
  int od = outdeg[i], idg = indeg[i];
  out_norm[i] = od > 0 ? rsqrtf((float)od) : 0.0f;
  in_norm[i]  = idg > 0 ? rsqrtf((float)idg) : 0.0f;
}

// ---------------- exclusive scan of indeg -> offsets ----------------
__global__ void scan1_kernel(const int* __restrict__ indeg, int N,
                             int* __restrict__ offsets, int* __restrict__ blocksums) {
  __shared__ int sd[256];
  int t = threadIdx.x;
  int base = blockIdx.x * 1024 + t * 4;
  int v0 = base + 0 < N ? indeg[base + 0] : 0;
  int v1 = base + 1 < N ? indeg[base + 1] : 0;
  int v2 = base + 2 < N ? indeg[base + 2] : 0;
  int v3 = base + 3 < N ? indeg[base + 3] : 0;
  int s = v0 + v1 + v2 + v3;
  sd[t] = s;
  __syncthreads();
  for (int d = 1; d < 256; d <<= 1) {
    int tmp = (t >= d) ? sd[t - d] : 0;
    __syncthreads();
    if (t >= d) sd[t] += tmp;
    __syncthreads();
  }
  int excl = sd[t] - s;
  if (base + 0 < N) offsets[base + 0] = excl;
  if (base + 1 < N) offsets[base + 1] = excl + v0;
  if (base + 2 < N) offsets[base + 2] = excl + v0 + v1;
  if (base + 3 < N) offsets[base + 3] = excl + v0 + v1 + v2;
  if (t == 0) blocksums[blockIdx.x] = sd[255];
}

__global__ void scan2_kernel(int* __restrict__ blocksums, int NB,
                             int* __restrict__ offsets, int N) {
  __shared__ int sd[256];
  int t = threadIdx.x;
  int v = (t < NB) ? blocksums[t] : 0;
  sd[t] = v;
  __syncthreads();
  for (int d = 1; d < 256; d <<= 1) {
    int tmp = (t >= d) ? sd[t - d] : 0;
    __syncthreads();
    if (t >= d) sd[t] += tmp;
    __syncthreads();
  }
  if (t < NB) blocksums[t] = sd[t] - v;   // exclusive
  if (t == 255) offsets[N] = sd[255];     // total = E
}

__global__ void scan3_kernel(int* __restrict__ offsets, const int* __restrict__ blocksums, int N) {
  int stride = gridDim.x * blockDim.x;
  for (int i = blockIdx.x * blockDim.x + threadIdx.x; i < N; i += stride)
    offsets[i] += blocksums[i >> 10];
}

// ---------------- CSR fill (dst -> list of src) ----------------
__global__ void fill_kernel(const int* __restrict__ src, const int* __restrict__ dst, int E,
                            const int* __restrict__ offsets, int* __restrict__ cursor,
                            int* __restrict__ csr) {
  int stride = gridDim.x * blockDim.x;
  for (int e = blockIdx.x * blockDim.x + threadIdx.x; e < E; e += stride) {
    int v = dst[e];
    int p = atomicAdd(&cursor[v], 1);
    csr[offsets[v] + p] = src[e];
  }
}

// ---------------- fused GEMM: y = diag(norm)*(x@Wy) [128 cols], z (+)= x@Wz [64 cols] ----------------
__global__ __launch_bounds__(256, 3)
void gemm_kernel(const float* __restrict__ x, int N,
                 const float* __restrict__ Wy, float* __restrict__ yout,
                 const float* __restrict__ rownorm, int ny_blocks,
                 const float* __restrict__ Wz, float* __restrict__ zout, int z_accum) {
  __shared__ float As[BK][BMP];
  __shared__ float Bs[BK][BN];
  const int tid = threadIdx.x;
  const int tx = tid & 7;    // col group (8 cols each)
  const int ty = tid >> 3;   // row group (8 rows each), 0..31
  const int row0 = blockIdx.x * BM;
  const bool is_y = (int)blockIdx.y < ny_blocks;
  const float* __restrict__ W = is_y ? Wy : Wz;
  const int ldW = is_y ? 128 : 64;
  const int wcol = is_y ? (int)blockIdx.y * 64 : ((int)blockIdx.y - ny_blocks) * 64;

  float acc[8][8];
#pragma unroll
  for (int i = 0; i < 8; ++i)
#pragma unroll
    for (int j = 0; j < 8; ++j) acc[i][j] = 0.f;

  const int lk = (tid & 7) * 4;   // k offset for x loads
  const int lm0 = tid >> 3;       // base row for x loads
  const int wn4 = (tid & 15) * 4; // n offset for W loads
  const int wk = tid >> 4;        // k base for W loads

  for (int k0 = 0; k0 < 128; k0 += BK) {
#pragma unroll
    for (int mi = 0; mi < 8; ++mi) {
      int m = lm0 + mi * 32;
      int r = row0 + m;
      float4 v = make_float4(0.f, 0.f, 0.f, 0.f);
      if (r < N) v = *(const float4*)(x + (size_t)r * 128 + k0 + lk);
      As[lk + 0][m] = v.x;
      As[lk + 1][m] = v.y;
      As[lk + 2][m] = v.z;
      As[lk + 3][m] = v.w;
    }
#pragma unroll
    for (int it = 0; it < 2; ++it) {
      int k = wk + it * 16;
      float4 w = *(const float4*)(W + (size_t)(k0 + k) * ldW + wcol + wn4);
      *(float4*)&Bs[k][wn4] = w;
    }
    __syncthreads();
#pragma unroll 8
    for (int k = 0; k < BK; ++k) {
      float4 a0 = *(const float4*)&As[k][ty * 8];
      float4 a1 = *(const float4*)&As[k][ty * 8 + 4];
      float4 b0 = *(const float4*)&Bs[k][tx * 8];
      float4 b1 = *(const float4*)&Bs[k][tx * 8 + 4];
      float a[8] = {a0.x, a0.y, a0.z, a0.w, a1.x, a1.y, a1.z, a1.w};
      float b[8] = {b0.x, b0.y, b0.z, b0.w, b1.x, b1.y, b1.z, b1.w};
#pragma unroll
      for (int i = 0; i < 8; ++i)
#pragma unroll
        for (int j = 0; j < 8; ++j)
          acc[i][j] = fmaf(a[i], b[j], acc[i][j]);
    }
    __syncthreads();
  }

#pragma unroll
  for (int i = 0; i < 8; ++i) {
    int r = row0 + ty * 8 + i;
    if (r >= N) continue;
    if (is_y) {
      float s = rownorm[r];
      float* yp = yout + (size_t)r * 128 + wcol + tx * 8;
      float4 v0 = make_float4(acc[i][0] * s, acc[i][1] * s, acc[i][2] * s, acc[i][3] * s);
      float4 v1 = make_float4(acc[i][4] * s, acc[i][5] * s, acc[i][6] * s, acc[i][7] * s);
      *(float4*)(yp) = v0;
      *(float4*)(yp + 4) = v1;
    } else {
      float* zp = zout + (size_t)r * 64 + wcol + tx * 8;
      float4 v0 = make_float4(acc[i][0], acc[i][1], acc[i][2], acc[i][3]);
      float4 v1 = make_float4(acc[i][4], acc[i][5], acc[i][6], acc[i][7]);
      if (z_accum) {
        float4 o0 = *(float4*)(zp);
        float4 o1 = *(float4*)(zp + 4);
        v0.x += o0.x; v0.y += o0.y; v0.z += o0.z; v0.w += o0.w;
        v1.x += o1.x; v1.y += o1.y; v1.z += o1.z; v1.w += o1.w;
      }
      *(float4*)(zp) = v0;
      *(float4*)(zp + 4) = v1;
    }
  }
}

// ---------------- aggregation: h[v] = relu(in_norm[v]*sum_{s in csr[v]} y[s] + b) ----------------
__global__ void agg_kernel(const float* __restrict__ y, float* __restrict__ h,
                           const int* __restrict__ csr, const int* __restrict__ offsets,
                           const float* __restrict__ in_norm, const float* __restrict__ bias,
                           int N) {
  int node = blockIdx.x * 2 + (threadIdx.x >> 7);
  int c = threadIdx.x & 127;
  if (node >= N) return;
  int off = offsets[node];
  int end = offsets[node + 1];
  float acc = 0.f;
  int i = off;
  for (; i + 4 <= end; i += 4) {
    int s0 = csr[i], s1 = csr[i + 1], s2 = csr[i + 2], s3 = csr[i + 3];
    float a0 = y[(size_t)s0 * 128 + c];
    float a1 = y[(size_t)s1 * 128 + c];
    float a2 = y[(size_t)s2 * 128 + c];
    float a3 = y[(size_t)s3 * 128 + c];
    acc += a0 + a1 + a2 + a3;
  }
  for (; i < end; ++i) acc += y[(size_t)csr[i] * 128 + c];
  h[(size_t)node * 128 + c] = fmaxf(fmaf(acc, in_norm[node], bias[c]), 0.f);
}

// ---------------- pooling: out[v] = bo + sum_{s in csr[v]} z[s] ----------------
__global__ void pool_kernel(const float* __restrict__ z, float* __restrict__ out,
                            const int* __restrict__ csr, const int* __restrict__ offsets,
                            const float* __restrict__ bo, int N) {
  int node = blockIdx.x * 4 + (threadIdx.x >> 6);
  int c = threadIdx.x & 63;
  if (node >= N) return;
  int off = offsets[node];
  int end = offsets[node + 1];
  float acc = 0.f;
  int i = off;
  for (; i + 4 <= end; i += 4) {
    int s0 = csr[i], s1 = csr[i + 1], s2 = csr[i + 2], s3 = csr[i + 3];
    acc += z[(size_t)s0 * 64 + c] + z[(size_t)s1 * 64 + c] +
           z[(size_t)s2 * 64 + c] + z[(size_t)s3 * 64 + c];
  }
  for (; i < end; ++i) acc += z[(size_t)csr[i] * 64 + c];
  out[(size_t)node * 64 + c] = acc + bo[c];
}

extern "C" void kernel_launch(void* const* d_in, const int* in_sizes, int n_in,
                              void* d_out, int out_size, void* d_ws, size_t ws_size,
                              hipStream_t stream) {
  const float* feats = (const float*)d_in[0];
  const int* src = (const int*)d_in[1];
  const int* dst = (const int*)d_in[2];
  const float* W0 = (const float*)d_in[3];
  const float* b0 = (const float*)d_in[4];
  const float* W1 = (const float*)d_in[5];
  const float* b1 = (const float*)d_in[6];
  const float* W2 = (const float*)d_in[7];
  const float* b2 = (const float*)d_in[8];
  const float* Wo = (const float*)d_in[9];
  const float* bo = (const float*)d_in[10];
  float* out = (float*)d_out;

  const int N = in_sizes[0] / 128;
  const int E = in_sizes[1];

  char* p = (char*)d_ws;
  auto take = [&](size_t bytes) { char* q = p; p += (bytes + 255) & ~(size_t)255; return q; };
  float* A        = (float*)take((size_t)N * 128 * 4);  // y buffer
  float* B        = (float*)take((size_t)N * 128 * 4);  // h buffer
  float* Z        = (float*)take((size_t)N * 64 * 4);   // z accumulator
  float* out_norm = (float*)take((size_t)N * 4);
  float* in_norm  = (float*)take((size_t)N * 4);
  int* outdeg     = (int*)take((size_t)N * 4);
  int* indeg      = (int*)take((size_t)N * 4);
  int* cursor     = (int*)take((size_t)N * 4);
  int* offsets    = (int*)take((size_t)(N + 1) * 4);
  int* blocksums  = (int*)take(1024);
  int* csr        = (int*)take((size_t)E * 4);
  (void)ws_size; (void)n_in; (void)out_size;

  hipMemsetAsync(outdeg, 0, (size_t)N * 4, stream);
  hipMemsetAsync(indeg, 0, (size_t)N * 4, stream);
  hipMemsetAsync(cursor, 0, (size_t)N * 4, stream);

  deg_kernel<<<1024, 256, 0, stream>>>(src, dst, E, outdeg, indeg);
  norm_kernel<<<(N + 255) / 256, 256, 0, stream>>>(outdeg, indeg, N, out_norm, in_norm);
  int NB = (N + 1023) / 1024;
  scan1_kernel<<<NB, 256, 0, stream>>>(indeg, N, offsets, blocksums);
  scan2_kernel<<<1, 256, 0, stream>>>(blocksums, NB, offsets, N);
  scan3_kernel<<<1024, 256, 0, stream>>>(offsets, blocksums, N);
  fill_kernel<<<1024, 256, 0, stream>>>(src, dst, E, offsets, cursor, csr);

  dim3 blk(256);
  int rb = (N + BM - 1) / BM;
  // layer 1: y1 = diag(out_norm)*(feats@W0)
  gemm_kernel<<<dim3(rb, 2), blk, 0, stream>>>(feats, N, W0, A, out_norm, 2, nullptr, nullptr, 0);
  agg_kernel<<<(N + 1) / 2, blk, 0, stream>>>(A, B, csr, offsets, in_norm, b0, N);
  // layer 2: y2 = diag(out_norm)*(h1@W1); z = h1@Wo[0:128]
  gemm_kernel<<<dim3(rb, 3), blk, 0, stream>>>(B, N, W1, A, out_norm, 2, Wo, Z, 0);
  agg_kernel<<<(N + 1) / 2, blk, 0, stream>>>(A, B, csr, offsets, in_norm, b1, N);
  // layer 3: y3 = diag(out_norm)*(h2@W2); z += h2@Wo[128:256]
  gemm_kernel<<<dim3(rb, 3), blk, 0, stream>>>(B, N, W2, A, out_norm, 2, Wo + 128 * 64, Z, 1);
  agg_kernel<<<(N + 1) / 2, blk, 0, stream>>>(A, B, csr, offsets, in_norm, b2, N);
  // z += h3@Wo[256:384]
  gemm_kernel<<<dim3(rb, 1), blk, 0, stream>>>(B, N, nullptr, nullptr, nullptr, 0, Wo + 256 * 64, Z, 1);
  // out = segment_sum(z[src], dst) + bo
  pool_kernel<<<(N + 3) / 4, blk, 0, stream>>>(Z, out, csr, offsets, bo, N);
}

// Round 2
// 599.912 us; speedup vs baseline: 1.6859x; 1.6859x over previous
//
#include <hip/hip_runtime.h>

typedef unsigned int uint;
typedef unsigned short ushort;
typedef __bf16 bf16x8 __attribute__((ext_vector_type(8)));
typedef float f32x4 __attribute__((ext_vector_type(4)));

__device__ __forceinline__ ushort f2b(float f) {
  union { float f; uint u; } x; x.f = f;
  uint r = x.u + 0x7fff + ((x.u >> 16) & 1);
  return (ushort)(r >> 16);
}
__device__ __forceinline__ float b2f(uint s) {
  union { uint u; float f; } x; x.u = s << 16;
  return x.f;
}

__device__ __forceinline__ void gload_lds16(const void* g, void* l) {
  __builtin_amdgcn_global_load_lds(
      (const __attribute__((address_space(1))) void*)g,
      (__attribute__((address_space(3))) void*)l, 16, 0, 0);
}

// ---------------- degree ----------------
__global__ void deg_kernel(const int* __restrict__ src, const int* __restrict__ dst,
                           int E, int* __restrict__ outdeg, int* __restrict__ indeg) {
  int stride = gridDim.x * blockDim.x;
  for (int e = blockIdx.x * blockDim.x + threadIdx.x; e < E; e += stride) {
    atomicAdd(&outdeg[src[e]], 1);
    atomicAdd(&indeg[dst[e]], 1);
  }
}

__global__ void norm_kernel(const int* __restrict__ outdeg, const int* __restrict__ indeg,
                            int N, float* __restrict__ out_norm, float* __restrict__ in_norm) {
  int i = blockIdx.x * blockDim.x + threadIdx.x;
  if (i >= N) return;
  int od = outdeg[i], idg = indeg[i];
  out_norm[i] = od > 0 ? rsqrtf((float)od) : 0.0f;
  in_norm[i]  = idg > 0 ? rsqrtf((float)idg) : 0.0f;
}

// ---------------- exclusive scan of indeg -> offsets ----------------
__global__ void scan1_kernel(const int* __restrict__ indeg, int N,
                             int* __restrict__ offsets, int* __restrict__ blocksums) {
  __shared__ int sd[256];
  int t = threadIdx.x;
  int base = blockIdx.x * 1024 + t * 4;
  int v0 = base + 0 < N ? indeg[base + 0] : 0;
  int v1 = base + 1 < N ? indeg[base + 1] : 0;
  int v2 = base + 2 < N ? indeg[base + 2] : 0;
  int v3 = base + 3 < N ? indeg[base + 3] : 0;
  int s = v0 + v1 + v2 + v3;
  sd[t] = s;
  __syncthreads();
  for (int d = 1; d < 256; d <<= 1) {
    int tmp = (t >= d) ? sd[t - d] : 0;
    __syncthreads();
    if (t >= d) sd[t] += tmp;
    __syncthreads();
  }
  int excl = sd[t] - s;
  if (base + 0 < N) offsets[base + 0] = excl;
  if (base + 1 < N) offsets[base + 1] = excl + v0;
  if (base + 2 < N) offsets[base + 2] = excl + v0 + v1;
  if (base + 3 < N) offsets[base + 3] = excl + v0 + v1 + v2;
  if (t == 0) blocksums[blockIdx.x] = sd[255];
}

__global__ void scan2_kernel(int* __restrict__ blocksums, int NB_,
                             int* __restrict__ offsets, int N) {
  __shared__ int sd[256];
  int t = threadIdx.x;
  int v = (t < NB_) ? blocksums[t] : 0;
  sd[t] = v;
  __syncthreads();
  for (int d = 1; d < 256; d <<= 1) {
    int tmp = (t >= d) ? sd[t - d] : 0;
    __syncthreads();
    if (t >= d) sd[t] += tmp;
    __syncthreads();
  }
  if (t < NB_) blocksums[t] = sd[t] - v;
  if (t == 255) offsets[N] = sd[255];
}

__global__ void scan3_kernel(int* __restrict__ offsets, const int* __restrict__ blocksums, int N) {
  int stride = gridDim.x * blockDim.x;
  for (int i = blockIdx.x * blockDim.x + threadIdx.x; i < N; i += stride)
    offsets[i] += blocksums[i >> 10];
}

// ---------------- CSR fill (dst -> list of src) ----------------
__global__ void fill_kernel(const int* __restrict__ src, const int* __restrict__ dst, int E,
                            const int* __restrict__ offsets, int* __restrict__ cursor,
                            int* __restrict__ csr) {
  int stride = gridDim.x * blockDim.x;
  for (int e = blockIdx.x * blockDim.x + threadIdx.x; e < E; e += stride) {
    int v = dst[e];
    int p = atomicAdd(&cursor[v], 1);
    csr[offsets[v] + p] = src[e];
  }
}

// ---------------- prep: feats fp32 -> bf16 swizzled rows ----------------
__global__ void prep_x(const float* __restrict__ feats, uint* __restrict__ xb, int total) {
  int stride = gridDim.x * blockDim.x;
  for (int i = blockIdx.x * blockDim.x + threadIdx.x; i < total; i += stride) {
    int node = i >> 6, j = i & 63;
    float2 f = *(const float2*)(feats + (size_t)i * 2);
    uint lo = f2b(f.x), hi = f2b(f.y);
    xb[node * 64 + (j ^ ((node & 7) << 2))] = lo | (hi << 16);
  }
}

// ---------------- prep: weights -> bf16 [n][k] transposed, swizzled ----------------
// Wt1: 128 rows (W0^T); Wt2: 192 rows (W1^T | Wo[0:128]^T);
// Wt3: 192 rows (W2^T | Wo[128:256]^T); Wt4: 64 rows (Wo[256:384]^T).
__global__ void prep_w(const float* __restrict__ W0, const float* __restrict__ W1,
                       const float* __restrict__ W2, const float* __restrict__ Wo,
                       ushort* __restrict__ Wt1, ushort* __restrict__ Wt2,
                       ushort* __restrict__ Wt3, ushort* __restrict__ Wt4) {
  int rid = blockIdx.x;   // 0..575
  int t = threadIdx.x;    // 0..63
  ushort* dst; const float* srcbase; int srcstride; int row;
  if (rid < 128)      { dst = Wt1; row = rid;        srcbase = W0 + row; srcstride = 128; }
  else if (rid < 320) { dst = Wt2; row = rid - 128;
    if (row < 128) { srcbase = W1 + row; srcstride = 128; }
    else           { srcbase = Wo + (row - 128); srcstride = 64; } }
  else if (rid < 512) { dst = Wt3; row = rid - 320;
    if (row < 128) { srcbase = W2 + row; srcstride = 128; }
    else           { srcbase = Wo + 128 * 64 + (row - 128); srcstride = 64; } }
  else                { dst = Wt4; row = rid - 512; srcbase = Wo + 256 * 64 + row; srcstride = 64; }
#pragma unroll
  for (int kk = 0; kk < 2; ++kk) {
    int k = t + kk * 64;
    float v = srcbase[(size_t)k * srcstride];
    dst[row * 128 + (k ^ ((row & 7) << 3))] = f2b(v);
  }
}

// ---------------- MFMA GEMM: per-block 128 rows x NB cols, K=128 in one LDS tile ----------------
// HASY: first 128 cols -> y (bf16, *out_norm). z slab (64 cols):
// ZMODE 0=none, 1=init fp32, 2=accum fp32, 3=accum + write bf16 final.
template <int NB, bool HASY, int ZMODE>
__global__ __launch_bounds__(256)
void gemm_mfma(const ushort* __restrict__ xb, int N,
               const ushort* __restrict__ wt,
               ushort* __restrict__ y, const float* __restrict__ onorm,
               float* __restrict__ z, ushort* __restrict__ zb) {
  constexpr int NT = NB / 16;
  __shared__ ushort As[128 * 128];
  __shared__ ushort Bs[NB * 128];
  const int tid = threadIdx.x;
  const int row0 = blockIdx.x * 128;

  const ushort* srcA = xb + (size_t)row0 * 128;
#pragma unroll
  for (int it = 0; it < 8; ++it)
    gload_lds16(srcA + it * 2048 + tid * 8, &As[it * 2048 + tid * 8]);
#pragma unroll
  for (int it = 0; it < NB / 16; ++it)
    gload_lds16(wt + it * 2048 + tid * 8, &Bs[it * 2048 + tid * 8]);
  __syncthreads();

  const int w = tid >> 6, l = tid & 63;
  const int lr = l & 15, lg = l >> 4;

  bf16x8 a[2][4];
#pragma unroll
  for (int mt = 0; mt < 2; ++mt)
#pragma unroll
    for (int kk = 0; kk < 4; ++kk) {
      int row = w * 32 + mt * 16 + lr;
      int idx = (row * 128 + kk * 32 + lg * 8) ^ ((row & 7) << 3);
      a[mt][kk] = *(const bf16x8*)&As[idx];
    }

  f32x4 acc[2][NT];
#pragma unroll
  for (int mt = 0; mt < 2; ++mt)
#pragma unroll
    for (int nt = 0; nt < NT; ++nt) acc[mt][nt] = (f32x4)0.f;

#pragma unroll
  for (int nt = 0; nt < NT; ++nt) {
    bf16x8 b[4];
#pragma unroll
    for (int kk = 0; kk < 4; ++kk) {
      int row = nt * 16 + lr;
      int idx = (row * 128 + kk * 32 + lg * 8) ^ ((row & 7) << 3);
      b[kk] = *(const bf16x8*)&Bs[idx];
    }
#pragma unroll
    for (int mt = 0; mt < 2; ++mt)
#pragma unroll
      for (int kk = 0; kk < 4; ++kk)
        acc[mt][nt] = __builtin_amdgcn_mfma_f32_16x16x32_bf16(a[mt][kk], b[kk], acc[mt][nt], 0, 0, 0);
  }

  float norms[2][4];
  if (HASY) {
#pragma unroll
    for (int mt = 0; mt < 2; ++mt)
#pragma unroll
      for (int j = 0; j < 4; ++j) {
        int r = row0 + w * 32 + mt * 16 + lg * 4 + j;
        norms[mt][j] = (r < N) ? onorm[r] : 0.f;
      }
  }

#pragma unroll
  for (int mt = 0; mt < 2; ++mt)
#pragma unroll
    for (int j = 0; j < 4; ++j) {
      int r = row0 + w * 32 + mt * 16 + lg * 4 + j;
      if (r >= N) continue;
#pragma unroll
      for (int nt = 0; nt < NT; ++nt) {
        int c = nt * 16 + lr;
        float v = acc[mt][nt][j];
        if (HASY && c < 128) {
          y[r * 128 + c] = f2b(v * norms[mt][j]);
        } else {
          int zc = c - (HASY ? 128 : 0);
          if (ZMODE == 1) z[r * 64 + zc] = v;
          else if (ZMODE == 2) z[r * 64 + zc] += v;
          else if (ZMODE == 3) zb[r * 64 + zc] = f2b(z[r * 64 + zc] + v);
        }
      }
    }
}

// ---------------- aggregation: h[v] = bf16(relu(in_norm[v]*sum y[s] + b)), swizzled ----------------
__global__ void agg_kernel(const ushort* __restrict__ y, uint* __restrict__ h,
                           const int* __restrict__ csr, const int* __restrict__ offsets,
                           const float* __restrict__ in_norm, const float* __restrict__ bias,
                           int N) {
  int node = blockIdx.x * 4 + (threadIdx.x >> 6);
  int j = threadIdx.x & 63;
  if (node >= N) return;
  const uint* yp = (const uint*)y;
  int off = offsets[node], end = offsets[node + 1];
  float a0 = 0.f, a1 = 0.f;
  int i = off;
  for (; i + 4 <= end; i += 4) {
    int s0 = csr[i], s1 = csr[i + 1], s2 = csr[i + 2], s3 = csr[i + 3];
    uint v0 = yp[s0 * 64 + j];
    uint v1 = yp[s1 * 64 + j];
    uint v2 = yp[s2 * 64 + j];
    uint v3 = yp[s3 * 64 + j];
    a0 += b2f(v0 & 0xffff) + b2f(v1 & 0xffff) + b2f(v2 & 0xffff) + b2f(v3 & 0xffff);
    a1 += b2f(v0 >> 16) + b2f(v1 >> 16) + b2f(v2 >> 16) + b2f(v3 >> 16);
  }
  for (; i < end; ++i) {
    uint v = yp[csr[i] * 64 + j];
    a0 += b2f(v & 0xffff);
    a1 += b2f(v >> 16);
  }
  float s = in_norm[node];
  float r0 = fmaxf(fmaf(a0, s, bias[2 * j]), 0.f);
  float r1 = fmaxf(fmaf(a1, s, bias[2 * j + 1]), 0.f);
  h[node * 64 + (j ^ ((node & 7) << 2))] = (uint)f2b(r0) | ((uint)f2b(r1) << 16);
}

// ---------------- pooling: out[v] = bo + sum zb[s] ----------------
__global__ void pool_kernel(const ushort* __restrict__ zb, float* __restrict__ out,
                            const int* __restrict__ csr, const int* __restrict__ offsets,
                            const float* __restrict__ bo, int N) {
  int node = blockIdx.x * 8 + (threadIdx.x >> 5);
  int j = threadIdx.x & 31;
  if (node >= N) return;
  const uint* zp = (const uint*)zb;
  int off = offsets[node], end = offsets[node + 1];
  float a0 = 0.f, a1 = 0.f;
  int i = off;
  for (; i + 4 <= end; i += 4) {
    int s0 = csr[i], s1 = csr[i + 1], s2 = csr[i + 2], s3 = csr[i + 3];
    uint v0 = zp[s0 * 32 + j];
    uint v1 = zp[s1 * 32 + j];
    uint v2 = zp[s2 * 32 + j];
    uint v3 = zp[s3 * 32 + j];
    a0 += b2f(v0 & 0xffff) + b2f(v1 & 0xffff) + b2f(v2 & 0xffff) + b2f(v3 & 0xffff);
    a1 += b2f(v0 >> 16) + b2f(v1 >> 16) + b2f(v2 >> 16) + b2f(v3 >> 16);
  }
  for (; i < end; ++i) {
    uint v = zp[csr[i] * 32 + j];
    a0 += b2f(v & 0xffff);
    a1 += b2f(v >> 16);
  }
  float2 o;
  o.x = a0 + bo[2 * j];
  o.y = a1 + bo[2 * j + 1];
  *(float2*)(out + node * 64 + 2 * j) = o;
}

extern "C" void kernel_launch(void* const* d_in, const int* in_sizes, int n_in,
                              void* d_out, int out_size, void* d_ws, size_t ws_size,
                              hipStream_t stream) {
  const float* feats = (const float*)d_in[0];
  const int* src = (const int*)d_in[1];
  const int* dst = (const int*)d_in[2];
  const float* W0 = (const float*)d_in[3];
  const float* b0 = (const float*)d_in[4];
  const float* W1 = (const float*)d_in[5];
  const float* b1 = (const float*)d_in[6];
  const float* W2 = (const float*)d_in[7];
  const float* b2 = (const float*)d_in[8];
  const float* Wo = (const float*)d_in[9];
  const float* bo = (const float*)d_in[10];
  float* out = (float*)d_out;

  const int N = in_sizes[0] / 128;
  const int E = in_sizes[1];
  const int NP = (N + 127) & ~127;   // padded rows for full GEMM tiles

  char* p = (char*)d_ws;
  auto take = [&](size_t bytes) { char* q = p; p += (bytes + 255) & ~(size_t)255; return q; };
  ushort* xb     = (ushort*)take((size_t)NP * 128 * 2);  // bf16 feats, swizzled
  ushort* hbuf   = (ushort*)take((size_t)NP * 128 * 2);  // bf16 h, swizzled
  ushort* ybuf   = (ushort*)take((size_t)NP * 128 * 2);  // bf16 y (gather target)
  float*  zbuf   = (float*) take((size_t)NP * 64 * 4);   // fp32 z accumulator
  ushort* zbb    = (ushort*)take((size_t)NP * 64 * 2);   // bf16 z final (gather target)
  ushort* Wt1    = (ushort*)take((size_t)128 * 128 * 2);
  ushort* Wt2    = (ushort*)take((size_t)192 * 128 * 2);
  ushort* Wt3    = (ushort*)take((size_t)192 * 128 * 2);
  ushort* Wt4    = (ushort*)take((size_t)64 * 128 * 2);
  float* out_norm = (float*)take((size_t)N * 4);
  float* in_norm  = (float*)take((size_t)N * 4);
  int* outdeg     = (int*)take((size_t)N * 4);
  int* indeg      = (int*)take((size_t)N * 4);
  int* cursor     = (int*)take((size_t)N * 4);
  int* offsets    = (int*)take((size_t)(N + 1) * 4);
  int* blocksums  = (int*)take(1024);
  int* csr        = (int*)take((size_t)E * 4);
  (void)ws_size; (void)n_in; (void)out_size;

  hipMemsetAsync(outdeg, 0, (size_t)N * 4, stream);
  hipMemsetAsync(indeg, 0, (size_t)N * 4, stream);
  hipMemsetAsync(cursor, 0, (size_t)N * 4, stream);

  prep_w<<<576, 64, 0, stream>>>(W0, W1, W2, Wo, Wt1, Wt2, Wt3, Wt4);
  prep_x<<<2048, 256, 0, stream>>>(feats, (uint*)xb, N * 64);

  deg_kernel<<<1024, 256, 0, stream>>>(src, dst, E, outdeg, indeg);
  norm_kernel<<<(N + 255) / 256, 256, 0, stream>>>(outdeg, indeg, N, out_norm, in_norm);
  int NB_ = (N + 1023) / 1024;
  scan1_kernel<<<NB_, 256, 0, stream>>>(indeg, N, offsets, blocksums);
  scan2_kernel<<<1, 256, 0, stream>>>(blocksums, NB_, offsets, N);
  scan3_kernel<<<1024, 256, 0, stream>>>(offsets, blocksums, N);
  fill_kernel<<<1024, 256, 0, stream>>>(src, dst, E, offsets, cursor, csr);

  dim3 blk(256);
  int rb = NP / 128;
  int ab = (N + 3) / 4;

  // layer 1: y1 = diag(out_norm)*(feats@W0)
  gemm_mfma<128, true, 0><<<rb, blk, 0, stream>>>(xb, N, Wt1, ybuf, out_norm, nullptr, nullptr);
  agg_kernel<<<ab, blk, 0, stream>>>(ybuf, (uint*)hbuf, csr, offsets, in_norm, b0, N);
  // layer 2: y2 = diag(out_norm)*(h1@W1); z = h1@Wo[0:128]
  gemm_mfma<192, true, 1><<<rb, blk, 0, stream>>>(hbuf, N, Wt2, ybuf, out_norm, zbuf, nullptr);
  agg_kernel<<<ab, blk, 0, stream>>>(ybuf, (uint*)hbuf, csr, offsets, in_norm, b1, N);
  // layer 3: y3 = diag(out_norm)*(h2@W2); z += h2@Wo[128:256]
  gemm_mfma<192, true, 2><<<rb, blk, 0, stream>>>(hbuf, N, Wt3, ybuf, out_norm, zbuf, nullptr);
  agg_kernel<<<ab, blk, 0, stream>>>(ybuf, (uint*)hbuf, csr, offsets, in_norm, b2, N);
  // z += h3@Wo[256:384]; write bf16 z
  gemm_mfma<64, false, 3><<<rb, blk, 0, stream>>>(hbuf, N, Wt4, nullptr, nullptr, zbuf, zbb);
  // out = segment_sum(z[src], dst) + bo
  pool_kernel<<<(N + 7) / 8, blk, 0, stream>>>(zbb, out, csr, offsets, bo, N);
}

// Round 3
// 425.036 us; speedup vs baseline: 2.3795x; 1.4114x over previous
//
#include <hip/hip_runtime.h>

typedef unsigned int uint;
typedef unsigned short ushort;
typedef __bf16 bf16x8 __attribute__((ext_vector_type(8)));
typedef float f32x4 __attribute__((ext_vector_type(4)));

#define G1 512          // pass-1 blocks
#define SH 8            // 256 nodes per coarse bucket

__device__ __forceinline__ ushort f2b(float f) {
  union { float f; uint u; } x; x.f = f;
  uint r = x.u + 0x7fff + ((x.u >> 16) & 1);
  return (ushort)(r >> 16);
}
__device__ __forceinline__ float b2f(uint s) {
  union { uint u; float f; } x; x.u = s << 16;
  return x.f;
}

__device__ __forceinline__ void gload_lds16(const void* g, void* l) {
  __builtin_amdgcn_global_load_lds(
      (const __attribute__((address_space(1))) void*)g,
      (__attribute__((address_space(3))) void*)l, 16, 0, 0);
}

// ---------------- pass 1a: per-(block,bucket) histograms of dst and src ----------------
__global__ void p1hist(const int* __restrict__ src, const int* __restrict__ dst, int E,
                       int NBK, int SCN, int* __restrict__ H) {
  __shared__ int hd[512], hs[512];
  int t = threadIdx.x, b = blockIdx.x;
  hd[t] = 0; hd[t + 256] = 0; hs[t] = 0; hs[t + 256] = 0;
  __syncthreads();
  int chunk = (E + G1 - 1) / G1;
  int c0 = b * chunk, c1 = min(E, c0 + chunk);
  for (int e = c0 + t; e < c1; e += 256) {
    atomicAdd(&hd[dst[e] >> SH], 1);
    atomicAdd(&hs[src[e] >> SH], 1);
  }
  __syncthreads();
  for (int k = t; k < NBK; k += 256) {
    H[k * G1 + b] = hd[k];
    H[SCN + k * G1 + b] = hs[k];
  }
}

// ---------------- scan chain over H (length n) -> H2 exclusive ----------------
__global__ void scanA(const int* __restrict__ in, int n, int* __restrict__ out,
                      int* __restrict__ bsum) {
  __shared__ int sd[256];
  int t = threadIdx.x;
  int base = blockIdx.x * 2048 + t * 8;
  int v[8]; int s = 0;
#pragma unroll
  for (int k = 0; k < 8; ++k) { v[k] = (base + k < n) ? in[base + k] : 0; s += v[k]; }
  sd[t] = s;
  __syncthreads();
  for (int d = 1; d < 256; d <<= 1) {
    int tmp = (t >= d) ? sd[t - d] : 0;
    __syncthreads();
    if (t >= d) sd[t] += tmp;
    __syncthreads();
  }
  int run = sd[t] - s;
#pragma unroll
  for (int k = 0; k < 8; ++k) {
    if (base + k < n) out[base + k] = run;
    run += v[k];
  }
  if (t == 255) bsum[blockIdx.x] = sd[255];
}

__global__ void scanB(int* __restrict__ bsum, int NB_) {
  __shared__ int sd[256];
  int t = threadIdx.x;
  int v = (t < NB_) ? bsum[t] : 0;
  sd[t] = v;
  __syncthreads();
  for (int d = 1; d < 256; d <<= 1) {
    int tmp = (t >= d) ? sd[t - d] : 0;
    __syncthreads();
    if (t >= d) sd[t] += tmp;
    __syncthreads();
  }
  if (t < NB_) bsum[t] = sd[t] - v;
}

__global__ void scanC(int* __restrict__ out, const int* __restrict__ bsum, int n) {
  int stride = gridDim.x * blockDim.x;
  for (int i = blockIdx.x * blockDim.x + threadIdx.x; i < n; i += stride)
    out[i] += bsum[i >> 11];
}

// ---------------- pass 1b: scatter records into coarse buckets ----------------
__global__ void p1scatter(const int* __restrict__ src, const int* __restrict__ dst, int E,
                          int NBK, int SCN, const int* __restrict__ H2,
                          uint2* __restrict__ ebuf, uint* __restrict__ sbuf) {
  __shared__ int cd[512], cs[512];
  int t = threadIdx.x, b = blockIdx.x;
  for (int k = t; k < NBK; k += 256) {
    cd[k] = H2[k * G1 + b];
    cs[k] = H2[SCN + k * G1 + b] - E;
  }
  __syncthreads();
  int chunk = (E + G1 - 1) / G1;
  int c0 = b * chunk, c1 = min(E, c0 + chunk);
  for (int e = c0 + t; e < c1; e += 256) {
    int d = dst[e], s = src[e];
    int p = atomicAdd(&cd[d >> SH], 1);
    ebuf[p] = make_uint2((uint)d, (uint)s);
    int q = atomicAdd(&cs[s >> SH], 1);
    sbuf[q] = (uint)s;
  }
}

// ---------------- pass 2: per-bucket fine CSR + degrees/norms ----------------
__global__ void p2build(const uint2* __restrict__ ebuf, const uint* __restrict__ sbuf,
                        const int* __restrict__ H2, int E, int N, int NBK, int SCN,
                        int* __restrict__ offsets, int* __restrict__ csr,
                        float* __restrict__ out_norm, float* __restrict__ in_norm) {
  __shared__ int cnt[256], sd[256], cur[256];
  int t = threadIdx.x, buck = blockIdx.x;
  int base = buck << SH;
  int dbase = H2[buck * G1];
  int dend = (buck == NBK - 1) ? E : H2[(buck + 1) * G1];
  int sbase = H2[SCN + buck * G1] - E;
  int send = (buck == NBK - 1) ? E : (H2[SCN + (buck + 1) * G1] - E);

  // out-degree from src buckets
  cnt[t] = 0;
  __syncthreads();
  for (int i = sbase + t; i < send; i += 256) atomicAdd(&cnt[sbuf[i] & 255], 1);
  __syncthreads();
  if (base + t < N) out_norm[base + t] = cnt[t] > 0 ? rsqrtf((float)cnt[t]) : 0.f;
  __syncthreads();

  // in-degree
  cnt[t] = 0;
  __syncthreads();
  for (int i = dbase + t; i < dend; i += 256) atomicAdd(&cnt[ebuf[i].x & 255], 1);
  __syncthreads();
  int v = cnt[t];
  sd[t] = v;
  __syncthreads();
  for (int d = 1; d < 256; d <<= 1) {
    int tmp = (t >= d) ? sd[t - d] : 0;
    __syncthreads();
    if (t >= d) sd[t] += tmp;
    __syncthreads();
  }
  int excl = sd[t] - v;
  if (base + t < N) {
    offsets[base + t] = dbase + excl;
    in_norm[base + t] = v > 0 ? rsqrtf((float)v) : 0.f;
  }
  if (buck == NBK - 1 && t == 0) offsets[N] = E;
  cur[t] = dbase + excl;
  __syncthreads();
  for (int i = dbase + t; i < dend; i += 256) {
    uint2 r = ebuf[i];
    int p = atomicAdd(&cur[r.x & 255], 1);
    csr[p] = (int)r.y;
  }
}

// ---------------- prep: feats fp32 -> bf16 swizzled rows ----------------
__global__ void prep_x(const float* __restrict__ feats, uint* __restrict__ xb, int total) {
  int stride = gridDim.x * blockDim.x;
  for (int i = blockIdx.x * blockDim.x + threadIdx.x; i < total; i += stride) {
    int node = i >> 6, j = i & 63;
    float2 f = *(const float2*)(feats + (size_t)i * 2);
    uint lo = f2b(f.x), hi = f2b(f.y);
    xb[node * 64 + (j ^ ((node & 7) << 2))] = lo | (hi << 16);
  }
}

// ---------------- prep: weights -> bf16 [n][k] transposed, swizzled ----------------
__global__ void prep_w(const float* __restrict__ W0, const float* __restrict__ W1,
                       const float* __restrict__ W2, const float* __restrict__ Wo,
                       ushort* __restrict__ Wt1, ushort* __restrict__ Wt2,
                       ushort* __restrict__ Wt3, ushort* __restrict__ Wt4) {
  int rid = blockIdx.x;   // 0..575
  int t = threadIdx.x;    // 0..63
  ushort* dst; const float* srcbase; int srcstride; int row;
  if (rid < 128)      { dst = Wt1; row = rid;        srcbase = W0 + row; srcstride = 128; }
  else if (rid < 320) { dst = Wt2; row = rid - 128;
    if (row < 128) { srcbase = W1 + row; srcstride = 128; }
    else           { srcbase = Wo + (row - 128); srcstride = 64; } }
  else if (rid < 512) { dst = Wt3; row = rid - 320;
    if (row < 128) { srcbase = W2 + row; srcstride = 128; }
    else           { srcbase = Wo + 128 * 64 + (row - 128); srcstride = 64; } }
  else                { dst = Wt4; row = rid - 512; srcbase = Wo + 256 * 64 + row; srcstride = 64; }
#pragma unroll
  for (int kk = 0; kk < 2; ++kk) {
    int k = t + kk * 64;
    float v = srcbase[(size_t)k * srcstride];
    dst[row * 128 + (k ^ ((row & 7) << 3))] = f2b(v);
  }
}

// ---------------- MFMA GEMM: per-block 128 rows x NB cols, K=128 in one LDS tile ----------------
template <int NB, bool HASY, int ZMODE>
__global__ __launch_bounds__(256)
void gemm_mfma(const ushort* __restrict__ xb, int N,
               const ushort* __restrict__ wt,
               ushort* __restrict__ y, const float* __restrict__ onorm,
               float* __restrict__ z, ushort* __restrict__ zb) {
  constexpr int NT = NB / 16;
  __shared__ ushort As[128 * 128];
  __shared__ ushort Bs[NB * 128];
  const int tid = threadIdx.x;
  const int row0 = blockIdx.x * 128;

  const ushort* srcA = xb + (size_t)row0 * 128;
#pragma unroll
  for (int it = 0; it < 8; ++it)
    gload_lds16(srcA + it * 2048 + tid * 8, &As[it * 2048 + tid * 8]);
#pragma unroll
  for (int it = 0; it < NB / 16; ++it)
    gload_lds16(wt + it * 2048 + tid * 8, &Bs[it * 2048 + tid * 8]);
  __syncthreads();

  const int w = tid >> 6, l = tid & 63;
  const int lr = l & 15, lg = l >> 4;

  bf16x8 a[2][4];
#pragma unroll
  for (int mt = 0; mt < 2; ++mt)
#pragma unroll
    for (int kk = 0; kk < 4; ++kk) {
      int row = w * 32 + mt * 16 + lr;
      int idx = (row * 128 + kk * 32 + lg * 8) ^ ((row & 7) << 3);
      a[mt][kk] = *(const bf16x8*)&As[idx];
    }

  f32x4 acc[2][NT];
#pragma unroll
  for (int mt = 0; mt < 2; ++mt)
#pragma unroll
    for (int nt = 0; nt < NT; ++nt) acc[mt][nt] = (f32x4)0.f;

#pragma unroll
  for (int nt = 0; nt < NT; ++nt) {
    bf16x8 b[4];
#pragma unroll
    for (int kk = 0; kk < 4; ++kk) {
      int row = nt * 16 + lr;
      int idx = (row * 128 + kk * 32 + lg * 8) ^ ((row & 7) << 3);
      b[kk] = *(const bf16x8*)&Bs[idx];
    }
#pragma unroll
    for (int mt = 0; mt < 2; ++mt)
#pragma unroll
      for (int kk = 0; kk < 4; ++kk)
        acc[mt][nt] = __builtin_amdgcn_mfma_f32_16x16x32_bf16(a[mt][kk], b[kk], acc[mt][nt], 0, 0, 0);
  }

  float norms[2][4];
  if (HASY) {
#pragma unroll
    for (int mt = 0; mt < 2; ++mt)
#pragma unroll
      for (int j = 0; j < 4; ++j) {
        int r = row0 + w * 32 + mt * 16 + lg * 4 + j;
        norms[mt][j] = (r < N) ? onorm[r] : 0.f;
      }
  }

#pragma unroll
  for (int mt = 0; mt < 2; ++mt)
#pragma unroll
    for (int j = 0; j < 4; ++j) {
      int r = row0 + w * 32 + mt * 16 + lg * 4 + j;
      if (r >= N) continue;
#pragma unroll
      for (int nt = 0; nt < NT; ++nt) {
        int c = nt * 16 + lr;
        float v = acc[mt][nt][j];
        if (HASY && c < 128) {
          y[r * 128 + c] = f2b(v * norms[mt][j]);
        } else {
          int zc = c - (HASY ? 128 : 0);
          if (ZMODE == 1) z[r * 64 + zc] = v;
          else if (ZMODE == 2) z[r * 64 + zc] += v;
          else if (ZMODE == 3) zb[r * 64 + zc] = f2b(z[r * 64 + zc] + v);
        }
      }
    }
}

// ---------------- aggregation: h[v] = bf16(relu(in_norm[v]*sum y[s] + b)), swizzled ----------------
__global__ void agg_kernel(const ushort* __restrict__ y, uint* __restrict__ h,
                           const int* __restrict__ csr, const int* __restrict__ offsets,
                           const float* __restrict__ in_norm, const float* __restrict__ bias,
                           int N) {
  int node = blockIdx.x * 4 + (threadIdx.x >> 6);
  int j = threadIdx.x & 63;
  if (node >= N) return;
  const uint* yp = (const uint*)y;
  int off = offsets[node], end = offsets[node + 1];
  float a0 = 0.f, a1 = 0.f;
  int i = off;
  for (; i + 4 <= end; i += 4) {
    int s0 = csr[i], s1 = csr[i + 1], s2 = csr[i + 2], s3 = csr[i + 3];
    uint v0 = yp[s0 * 64 + j];
    uint v1 = yp[s1 * 64 + j];
    uint v2 = yp[s2 * 64 + j];
    uint v3 = yp[s3 * 64 + j];
    a0 += b2f(v0 & 0xffff) + b2f(v1 & 0xffff) + b2f(v2 & 0xffff) + b2f(v3 & 0xffff);
    a1 += b2f(v0 >> 16) + b2f(v1 >> 16) + b2f(v2 >> 16) + b2f(v3 >> 16);
  }
  for (; i < end; ++i) {
    uint v = yp[csr[i] * 64 + j];
    a0 += b2f(v & 0xffff);
    a1 += b2f(v >> 16);
  }
  float s = in_norm[node];
  float r0 = fmaxf(fmaf(a0, s, bias[2 * j]), 0.f);
  float r1 = fmaxf(fmaf(a1, s, bias[2 * j + 1]), 0.f);
  h[node * 64 + (j ^ ((node & 7) << 2))] = (uint)f2b(r0) | ((uint)f2b(r1) << 16);
}

// ---------------- pooling: out[v] = bo + sum zb[s] ----------------
__global__ void pool_kernel(const ushort* __restrict__ zb, float* __restrict__ out,
                            const int* __restrict__ csr, const int* __restrict__ offsets,
                            const float* __restrict__ bo, int N) {
  int node = blockIdx.x * 8 + (threadIdx.x >> 5);
  int j = threadIdx.x & 31;
  if (node >= N) return;
  const uint* zp = (const uint*)zb;
  int off = offsets[node], end = offsets[node + 1];
  float a0 = 0.f, a1 = 0.f;
  int i = off;
  for (; i + 4 <= end; i += 4) {
    int s0 = csr[i], s1 = csr[i + 1], s2 = csr[i + 2], s3 = csr[i + 3];
    uint v0 = zp[s0 * 32 + j];
    uint v1 = zp[s1 * 32 + j];
    uint v2 = zp[s2 * 32 + j];
    uint v3 = zp[s3 * 32 + j];
    a0 += b2f(v0 & 0xffff) + b2f(v1 & 0xffff) + b2f(v2 & 0xffff) + b2f(v3 & 0xffff);
    a1 += b2f(v0 >> 16) + b2f(v1 >> 16) + b2f(v2 >> 16) + b2f(v3 >> 16);
  }
  for (; i < end; ++i) {
    uint v = zp[csr[i] * 32 + j];
    a0 += b2f(v & 0xffff);
    a1 += b2f(v >> 16);
  }
  float2 o;
  o.x = a0 + bo[2 * j];
  o.y = a1 + bo[2 * j + 1];
  *(float2*)(out + node * 64 + 2 * j) = o;
}

extern "C" void kernel_launch(void* const* d_in, const int* in_sizes, int n_in,
                              void* d_out, int out_size, void* d_ws, size_t ws_size,
                              hipStream_t stream) {
  const float* feats = (const float*)d_in[0];
  const int* src = (const int*)d_in[1];
  const int* dst = (const int*)d_in[2];
  const float* W0 = (const float*)d_in[3];
  const float* b0 = (const float*)d_in[4];
  const float* W1 = (const float*)d_in[5];
  const float* b1 = (const float*)d_in[6];
  const float* W2 = (const float*)d_in[7];
  const float* b2 = (const float*)d_in[8];
  const float* Wo = (const float*)d_in[9];
  const float* bo = (const float*)d_in[10];
  float* out = (float*)d_out;

  const int N = in_sizes[0] / 128;
  const int E = in_sizes[1];
  const int NP = (N + 127) & ~127;
  const int NBK = (N + 255) >> SH;        // coarse buckets
  const int SCN = NBK * G1;               // per-stream histogram entries
  const int SCN2 = 2 * SCN;

  char* p = (char*)d_ws;
  auto take = [&](size_t bytes) { char* q = p; p += (bytes + 255) & ~(size_t)255; return q; };
  ushort* xb   = (ushort*)take((size_t)NP * 128 * 2);
  ushort* hbuf = (ushort*)take((size_t)NP * 128 * 2);
  ushort* ybuf = (ushort*)take((size_t)NP * 128 * 2);
  // z region (38.4 MB) aliases the temporary build arrays (22.6 MB):
  // build finishes before layer-2 GEMM first touches zbuf.
  char* zregion = take((size_t)NP * 64 * 4 + (size_t)NP * 64 * 2);
  float*  zbuf = (float*)zregion;
  ushort* zbb  = (ushort*)(zregion + (size_t)NP * 64 * 4);
  uint2* ebuf = (uint2*)zregion;
  uint*  sbuf = (uint*)(zregion + (size_t)E * 8);
  int*   H    = (int*)(zregion + (size_t)E * 8 + (size_t)E * 4);
  int*   H2   = H + SCN2;
  ushort* Wt1 = (ushort*)take((size_t)128 * 128 * 2);
  ushort* Wt2 = (ushort*)take((size_t)192 * 128 * 2);
  ushort* Wt3 = (ushort*)take((size_t)192 * 128 * 2);
  ushort* Wt4 = (ushort*)take((size_t)64 * 128 * 2);
  float* out_norm = (float*)take((size_t)N * 4);
  float* in_norm  = (float*)take((size_t)N * 4);
  int* offsets    = (int*)take((size_t)(N + 1) * 4);
  int* blocksums  = (int*)take(1024);
  int* csr        = (int*)take((size_t)E * 4);
  (void)ws_size; (void)n_in; (void)out_size;

  // ---- graph build (no global atomics) ----
  p1hist<<<G1, 256, 0, stream>>>(src, dst, E, NBK, SCN, H);
  int NBs = (SCN2 + 2047) / 2048;
  scanA<<<NBs, 256, 0, stream>>>(H, SCN2, H2, blocksums);
  scanB<<<1, 256, 0, stream>>>(blocksums, NBs);
  scanC<<<512, 256, 0, stream>>>(H2, blocksums, SCN2);
  p1scatter<<<G1, 256, 0, stream>>>(src, dst, E, NBK, SCN, H2, ebuf, sbuf);
  p2build<<<NBK, 256, 0, stream>>>(ebuf, sbuf, H2, E, N, NBK, SCN,
                                   offsets, csr, out_norm, in_norm);

  // ---- dense prep ----
  prep_w<<<576, 64, 0, stream>>>(W0, W1, W2, Wo, Wt1, Wt2, Wt3, Wt4);
  prep_x<<<2048, 256, 0, stream>>>(feats, (uint*)xb, N * 64);

  dim3 blk(256);
  int rb = NP / 128;
  int ab = (N + 3) / 4;

  gemm_mfma<128, true, 0><<<rb, blk, 0, stream>>>(xb, N, Wt1, ybuf, out_norm, nullptr, nullptr);
  agg_kernel<<<ab, blk, 0, stream>>>(ybuf, (uint*)hbuf, csr, offsets, in_norm, b0, N);
  gemm_mfma<192, true, 1><<<rb, blk, 0, stream>>>(hbuf, N, Wt2, ybuf, out_norm, zbuf, nullptr);
  agg_kernel<<<ab, blk, 0, stream>>>(ybuf, (uint*)hbuf, csr, offsets, in_norm, b1, N);
  gemm_mfma<192, true, 2><<<rb, blk, 0, stream>>>(hbuf, N, Wt3, ybuf, out_norm, zbuf, nullptr);
  agg_kernel<<<ab, blk, 0, stream>>>(ybuf, (uint*)hbuf, csr, offsets, in_norm, b2, N);
  gemm_mfma<64, false, 3><<<rb, blk, 0, stream>>>(hbuf, N, Wt4, nullptr, nullptr, zbuf, zbb);
  pool_kernel<<<(N + 7) / 8, blk, 0, stream>>>(zbb, out, csr, offsets, bo, N);
}

// Round 4
// 394.936 us; speedup vs baseline: 2.5609x; 1.0762x over previous
//
#include <hip/hip_runtime.h>

typedef unsigned int uint;
typedef unsigned short ushort;
typedef __bf16 bf16x8 __attribute__((ext_vector_type(8)));
typedef float f32x4 __attribute__((ext_vector_type(4)));

#define G1 512          // pass-1 blocks
#define SH 8            // 256 nodes per coarse bucket

__device__ __forceinline__ ushort f2b(float f) {
  union { float f; uint u; } x; x.f = f;
  uint r = x.u + 0x7fff + ((x.u >> 16) & 1);
  return (ushort)(r >> 16);
}
__device__ __forceinline__ float b2f(uint s) {
  union { uint u; float f; } x; x.u = s << 16;
  return x.f;
}

__device__ __forceinline__ void gload_lds16(const void* g, void* l) {
  __builtin_amdgcn_global_load_lds(
      (const __attribute__((address_space(1))) void*)g,
      (__attribute__((address_space(3))) void*)l, 16, 0, 0);
}

// ---------------- pass 1a: per-(block,bucket) histograms of dst and src ----------------
__global__ void p1hist(const int* __restrict__ src, const int* __restrict__ dst, int E,
                       int NBK, int SCN, int* __restrict__ H) {
  __shared__ int hd[512], hs[512];
  int t = threadIdx.x, b = blockIdx.x;
  hd[t] = 0; hd[t + 256] = 0; hs[t] = 0; hs[t + 256] = 0;
  __syncthreads();
  int chunk = (E + G1 - 1) / G1;
  int c0 = b * chunk, c1 = min(E, c0 + chunk);
  for (int e = c0 + t; e < c1; e += 256) {
    atomicAdd(&hd[dst[e] >> SH], 1);
    atomicAdd(&hs[src[e] >> SH], 1);
  }
  __syncthreads();
  for (int k = t; k < NBK; k += 256) {
    H[k * G1 + b] = hd[k];
    H[SCN + k * G1 + b] = hs[k];
  }
}

// ---------------- scan chain over H (length n) -> H2 exclusive ----------------
__global__ void scanA(const int* __restrict__ in, int n, int* __restrict__ out,
                      int* __restrict__ bsum) {
  __shared__ int sd[256];
  int t = threadIdx.x;
  int base = blockIdx.x * 2048 + t * 8;
  int v[8]; int s = 0;
#pragma unroll
  for (int k = 0; k < 8; ++k) { v[k] = (base + k < n) ? in[base + k] : 0; s += v[k]; }
  sd[t] = s;
  __syncthreads();
  for (int d = 1; d < 256; d <<= 1) {
    int tmp = (t >= d) ? sd[t - d] : 0;
    __syncthreads();
    if (t >= d) sd[t] += tmp;
    __syncthreads();
  }
  int run = sd[t] - s;
#pragma unroll
  for (int k = 0; k < 8; ++k) {
    if (base + k < n) out[base + k] = run;
    run += v[k];
  }
  if (t == 255) bsum[blockIdx.x] = sd[255];
}

__global__ void scanB(int* __restrict__ bsum, int NB_) {
  __shared__ int sd[256];
  int t = threadIdx.x;
  int v = (t < NB_) ? bsum[t] : 0;
  sd[t] = v;
  __syncthreads();
  for (int d = 1; d < 256; d <<= 1) {
    int tmp = (t >= d) ? sd[t - d] : 0;
    __syncthreads();
    if (t >= d) sd[t] += tmp;
    __syncthreads();
  }
  if (t < NB_) bsum[t] = sd[t] - v;
}

__global__ void scanC(int* __restrict__ out, const int* __restrict__ bsum, int n) {
  int stride = gridDim.x * blockDim.x;
  for (int i = blockIdx.x * blockDim.x + threadIdx.x; i < n; i += stride)
    out[i] += bsum[i >> 11];
}

// ---------------- pass 1b: scatter records into coarse buckets ----------------
__global__ void p1scatter(const int* __restrict__ src, const int* __restrict__ dst, int E,
                          int NBK, int SCN, const int* __restrict__ H2,
                          uint2* __restrict__ ebuf, uint* __restrict__ sbuf) {
  __shared__ int cd[512], cs[512];
  int t = threadIdx.x, b = blockIdx.x;
  for (int k = t; k < NBK; k += 256) {
    cd[k] = H2[k * G1 + b];
    cs[k] = H2[SCN + k * G1 + b] - E;
  }
  __syncthreads();
  int chunk = (E + G1 - 1) / G1;
  int c0 = b * chunk, c1 = min(E, c0 + chunk);
  for (int e = c0 + t; e < c1; e += 256) {
    int d = dst[e], s = src[e];
    int p = atomicAdd(&cd[d >> SH], 1);
    ebuf[p] = make_uint2((uint)d, (uint)s);
    int q = atomicAdd(&cs[s >> SH], 1);
    sbuf[q] = (uint)s;
  }
}

// ---------------- pass 2: per-bucket fine CSR + degrees/norms ----------------
__global__ void p2build(const uint2* __restrict__ ebuf, const uint* __restrict__ sbuf,
                        const int* __restrict__ H2, int E, int N, int NBK, int SCN,
                        int* __restrict__ offsets, int* __restrict__ csr,
                        float* __restrict__ out_norm, float* __restrict__ in_norm) {
  __shared__ int cnt[256], sd[256], cur[256];
  int t = threadIdx.x, buck = blockIdx.x;
  int base = buck << SH;
  int dbase = H2[buck * G1];
  int dend = (buck == NBK - 1) ? E : H2[(buck + 1) * G1];
  int sbase = H2[SCN + buck * G1] - E;
  int send = (buck == NBK - 1) ? E : (H2[SCN + (buck + 1) * G1] - E);

  cnt[t] = 0;
  __syncthreads();
  for (int i = sbase + t; i < send; i += 256) atomicAdd(&cnt[sbuf[i] & 255], 1);
  __syncthreads();
  if (base + t < N) out_norm[base + t] = cnt[t] > 0 ? rsqrtf((float)cnt[t]) : 0.f;
  __syncthreads();

  cnt[t] = 0;
  __syncthreads();
  for (int i = dbase + t; i < dend; i += 256) atomicAdd(&cnt[ebuf[i].x & 255], 1);
  __syncthreads();
  int v = cnt[t];
  sd[t] = v;
  __syncthreads();
  for (int d = 1; d < 256; d <<= 1) {
    int tmp = (t >= d) ? sd[t - d] : 0;
    __syncthreads();
    if (t >= d) sd[t] += tmp;
    __syncthreads();
  }
  int excl = sd[t] - v;
  if (base + t < N) {
    offsets[base + t] = dbase + excl;
    in_norm[base + t] = v > 0 ? rsqrtf((float)v) : 0.f;
  }
  if (buck == NBK - 1 && t == 0) offsets[N] = E;
  cur[t] = dbase + excl;
  __syncthreads();
  for (int i = dbase + t; i < dend; i += 256) {
    uint2 r = ebuf[i];
    int p = atomicAdd(&cur[r.x & 255], 1);
    csr[p] = (int)r.y;
  }
}

// ---------------- prep: feats fp32 -> bf16 swizzled rows ----------------
__global__ void prep_x(const float* __restrict__ feats, uint* __restrict__ xb, int total) {
  int stride = gridDim.x * blockDim.x;
  for (int i = blockIdx.x * blockDim.x + threadIdx.x; i < total; i += stride) {
    int node = i >> 6, j = i & 63;
    float2 f = *(const float2*)(feats + (size_t)i * 2);
    uint lo = f2b(f.x), hi = f2b(f.y);
    xb[node * 64 + (j ^ ((node & 7) << 2))] = lo | (hi << 16);
  }
}

// ---------------- prep: weights -> bf16 [n][k] transposed, swizzled ----------------
__global__ void prep_w(const float* __restrict__ W0, const float* __restrict__ W1,
                       const float* __restrict__ W2, const float* __restrict__ Wo,
                       ushort* __restrict__ Wt1, ushort* __restrict__ Wt2,
                       ushort* __restrict__ Wt3, ushort* __restrict__ Wt4) {
  int rid = blockIdx.x;   // 0..575
  int t = threadIdx.x;    // 0..63
  ushort* dst; const float* srcbase; int srcstride; int row;
  if (rid < 128)      { dst = Wt1; row = rid;        srcbase = W0 + row; srcstride = 128; }
  else if (rid < 320) { dst = Wt2; row = rid - 128;
    if (row < 128) { srcbase = W1 + row; srcstride = 128; }
    else           { srcbase = Wo + (row - 128); srcstride = 64; } }
  else if (rid < 512) { dst = Wt3; row = rid - 320;
    if (row < 128) { srcbase = W2 + row; srcstride = 128; }
    else           { srcbase = Wo + 128 * 64 + (row - 128); srcstride = 64; } }
  else                { dst = Wt4; row = rid - 512; srcbase = Wo + 256 * 64 + row; srcstride = 64; }
#pragma unroll
  for (int kk = 0; kk < 2; ++kk) {
    int k = t + kk * 64;
    float v = srcbase[(size_t)k * srcstride];
    dst[row * 128 + (k ^ ((row & 7) << 3))] = f2b(v);
  }
}

// ---------------- MFMA GEMM: per-block 128 rows x NB cols, K=128 in one LDS tile ----------------
template <int NB, bool HASY, int ZMODE>
__global__ __launch_bounds__(256)
void gemm_mfma(const ushort* __restrict__ xb, int N,
               const ushort* __restrict__ wt,
               ushort* __restrict__ y, const float* __restrict__ onorm,
               float* __restrict__ z, ushort* __restrict__ zb) {
  constexpr int NT = NB / 16;
  __shared__ ushort As[128 * 128];
  __shared__ ushort Bs[NB * 128];
  const int tid = threadIdx.x;
  const int row0 = blockIdx.x * 128;

  const ushort* srcA = xb + (size_t)row0 * 128;
#pragma unroll
  for (int it = 0; it < 8; ++it)
    gload_lds16(srcA + it * 2048 + tid * 8, &As[it * 2048 + tid * 8]);
#pragma unroll
  for (int it = 0; it < NB / 16; ++it)
    gload_lds16(wt + it * 2048 + tid * 8, &Bs[it * 2048 + tid * 8]);
  __syncthreads();

  const int w = tid >> 6, l = tid & 63;
  const int lr = l & 15, lg = l >> 4;

  bf16x8 a[2][4];
#pragma unroll
  for (int mt = 0; mt < 2; ++mt)
#pragma unroll
    for (int kk = 0; kk < 4; ++kk) {
      int row = w * 32 + mt * 16 + lr;
      int idx = (row * 128 + kk * 32 + lg * 8) ^ ((row & 7) << 3);
      a[mt][kk] = *(const bf16x8*)&As[idx];
    }

  f32x4 acc[2][NT];
#pragma unroll
  for (int mt = 0; mt < 2; ++mt)
#pragma unroll
    for (int nt = 0; nt < NT; ++nt) acc[mt][nt] = (f32x4)0.f;

#pragma unroll
  for (int nt = 0; nt < NT; ++nt) {
    bf16x8 b[4];
#pragma unroll
    for (int kk = 0; kk < 4; ++kk) {
      int row = nt * 16 + lr;
      int idx = (row * 128 + kk * 32 + lg * 8) ^ ((row & 7) << 3);
      b[kk] = *(const bf16x8*)&Bs[idx];
    }
#pragma unroll
    for (int mt = 0; mt < 2; ++mt)
#pragma unroll
      for (int kk = 0; kk < 4; ++kk)
        acc[mt][nt] = __builtin_amdgcn_mfma_f32_16x16x32_bf16(a[mt][kk], b[kk], acc[mt][nt], 0, 0, 0);
  }

  float norms[2][4];
  if (HASY) {
#pragma unroll
    for (int mt = 0; mt < 2; ++mt)
#pragma unroll
      for (int j = 0; j < 4; ++j) {
        int r = row0 + w * 32 + mt * 16 + lg * 4 + j;
        norms[mt][j] = (r < N) ? onorm[r] : 0.f;
      }
  }

#pragma unroll
  for (int mt = 0; mt < 2; ++mt)
#pragma unroll
    for (int j = 0; j < 4; ++j) {
      int r = row0 + w * 32 + mt * 16 + lg * 4 + j;
      if (r >= N) continue;
#pragma unroll
      for (int nt = 0; nt < NT; ++nt) {
        int c = nt * 16 + lr;
        float v = acc[mt][nt][j];
        if (HASY && c < 128) {
          y[r * 128 + c] = f2b(v * norms[mt][j]);
        } else {
          int zc = c - (HASY ? 128 : 0);
          if (ZMODE == 1) z[r * 64 + zc] = v;
          else if (ZMODE == 2) z[r * 64 + zc] += v;
          else if (ZMODE == 3) zb[r * 64 + zc] = f2b(z[r * 64 + zc] + v);
        }
      }
    }
}

// ---------------- aggregation (vectorized gather): one wave per node ----------------
// lane = 4 groups x 16 lanes; group g handles neighbor slot g, lane q covers
// uints 4q..4q+3 of the row (channels 8q..8q+7). uint4 loads = 1KB/wave-inst.
__global__ void agg_kernel(const ushort* __restrict__ y, uint* __restrict__ h,
                           const int* __restrict__ csr, const int* __restrict__ offsets,
                           const float* __restrict__ in_norm, const float* __restrict__ bias,
                           int N) {
  int node = blockIdx.x * 4 + (threadIdx.x >> 6);
  if (node >= N) return;
  const int l = threadIdx.x & 63;
  const int g = l >> 4;
  const int q = l & 15;
  const uint4* yp = (const uint4*)y;   // 16 uint4 per row
  int off = offsets[node], end = offsets[node + 1];
  float a[8];
#pragma unroll
  for (int k = 0; k < 8; ++k) a[k] = 0.f;

  int i = off;
  for (; i + 8 <= end; i += 8) {
    int s0 = csr[i + g];
    int s1 = csr[i + 4 + g];
    uint4 v0 = yp[(size_t)s0 * 16 + q];
    uint4 v1 = yp[(size_t)s1 * 16 + q];
    a[0] += b2f(v0.x & 0xffff); a[1] += b2f(v0.x >> 16);
    a[2] += b2f(v0.y & 0xffff); a[3] += b2f(v0.y >> 16);
    a[4] += b2f(v0.z & 0xffff); a[5] += b2f(v0.z >> 16);
    a[6] += b2f(v0.w & 0xffff); a[7] += b2f(v0.w >> 16);
    a[0] += b2f(v1.x & 0xffff); a[1] += b2f(v1.x >> 16);
    a[2] += b2f(v1.y & 0xffff); a[3] += b2f(v1.y >> 16);
    a[4] += b2f(v1.z & 0xffff); a[5] += b2f(v1.z >> 16);
    a[6] += b2f(v1.w & 0xffff); a[7] += b2f(v1.w >> 16);
  }
  if (i + 4 <= end) {
    int s0 = csr[i + g];
    uint4 v0 = yp[(size_t)s0 * 16 + q];
    a[0] += b2f(v0.x & 0xffff); a[1] += b2f(v0.x >> 16);
    a[2] += b2f(v0.y & 0xffff); a[3] += b2f(v0.y >> 16);
    a[4] += b2f(v0.z & 0xffff); a[5] += b2f(v0.z >> 16);
    a[6] += b2f(v0.w & 0xffff); a[7] += b2f(v0.w >> 16);
    i += 4;
  }
  if (i < end) {
    bool valid = (i + g) < end;
    int s0 = csr[valid ? (i + g) : (end - 1)];
    uint4 v0 = yp[(size_t)s0 * 16 + q];
    if (valid) {
      a[0] += b2f(v0.x & 0xffff); a[1] += b2f(v0.x >> 16);
      a[2] += b2f(v0.y & 0xffff); a[3] += b2f(v0.y >> 16);
      a[4] += b2f(v0.z & 0xffff); a[5] += b2f(v0.z >> 16);
      a[6] += b2f(v0.w & 0xffff); a[7] += b2f(v0.w >> 16);
    }
  }
#pragma unroll
  for (int k = 0; k < 8; ++k) {
    a[k] += __shfl_xor(a[k], 16);
    a[k] += __shfl_xor(a[k], 32);
  }
  if (g == 0) {
    float s = in_norm[node];
    float4 b0 = *(const float4*)(bias + 8 * q);
    float4 b1 = *(const float4*)(bias + 8 * q + 4);
    float r0 = fmaxf(fmaf(a[0], s, b0.x), 0.f);
    float r1 = fmaxf(fmaf(a[1], s, b0.y), 0.f);
    float r2 = fmaxf(fmaf(a[2], s, b0.z), 0.f);
    float r3 = fmaxf(fmaf(a[3], s, b0.w), 0.f);
    float r4 = fmaxf(fmaf(a[4], s, b1.x), 0.f);
    float r5 = fmaxf(fmaf(a[5], s, b1.y), 0.f);
    float r6 = fmaxf(fmaf(a[6], s, b1.z), 0.f);
    float r7 = fmaxf(fmaf(a[7], s, b1.w), 0.f);
    uint4 o;
    o.x = (uint)f2b(r0) | ((uint)f2b(r1) << 16);
    o.y = (uint)f2b(r2) | ((uint)f2b(r3) << 16);
    o.z = (uint)f2b(r4) | ((uint)f2b(r5) << 16);
    o.w = (uint)f2b(r6) | ((uint)f2b(r7) << 16);
    ((uint4*)h)[(size_t)node * 16 + (q ^ (node & 7))] = o;
  }
}

// ---------------- pooling (vectorized gather): one wave per node ----------------
// 8 groups x 8 lanes: group handles neighbor slot, lane p covers uints 4p..4p+3.
__global__ void pool_kernel(const ushort* __restrict__ zb, float* __restrict__ out,
                            const int* __restrict__ csr, const int* __restrict__ offsets,
                            const float* __restrict__ bo, int N) {
  int node = blockIdx.x * 4 + (threadIdx.x >> 6);
  if (node >= N) return;
  const int l = threadIdx.x & 63;
  const int g = l >> 3;
  const int p = l & 7;
  const uint4* zp = (const uint4*)zb;  // 8 uint4 per row
  int off = offsets[node], end = offsets[node + 1];
  float a[8];
#pragma unroll
  for (int k = 0; k < 8; ++k) a[k] = 0.f;

  int i = off;
  for (; i + 8 <= end; i += 8) {
    int s0 = csr[i + g];
    uint4 v0 = zp[(size_t)s0 * 8 + p];
    a[0] += b2f(v0.x & 0xffff); a[1] += b2f(v0.x >> 16);
    a[2] += b2f(v0.y & 0xffff); a[3] += b2f(v0.y >> 16);
    a[4] += b2f(v0.z & 0xffff); a[5] += b2f(v0.z >> 16);
    a[6] += b2f(v0.w & 0xffff); a[7] += b2f(v0.w >> 16);
  }
  if (i < end) {
    bool valid = (i + g) < end;
    int s0 = csr[valid ? (i + g) : (end - 1)];
    uint4 v0 = zp[(size_t)s0 * 8 + p];
    if (valid) {
      a[0] += b2f(v0.x & 0xffff); a[1] += b2f(v0.x >> 16);
      a[2] += b2f(v0.y & 0xffff); a[3] += b2f(v0.y >> 16);
      a[4] += b2f(v0.z & 0xffff); a[5] += b2f(v0.z >> 16);
      a[6] += b2f(v0.w & 0xffff); a[7] += b2f(v0.w >> 16);
    }
  }
#pragma unroll
  for (int k = 0; k < 8; ++k) {
    a[k] += __shfl_xor(a[k], 8);
    a[k] += __shfl_xor(a[k], 16);
    a[k] += __shfl_xor(a[k], 32);
  }
  if (g == 0) {
    float4 o0, o1;
    o0.x = a[0] + bo[8 * p + 0];
    o0.y = a[1] + bo[8 * p + 1];
    o0.z = a[2] + bo[8 * p + 2];
    o0.w = a[3] + bo[8 * p + 3];
    o1.x = a[4] + bo[8 * p + 4];
    o1.y = a[5] + bo[8 * p + 5];
    o1.z = a[6] + bo[8 * p + 6];
    o1.w = a[7] + bo[8 * p + 7];
    float* op = out + (size_t)node * 64 + 8 * p;
    *(float4*)op = o0;
    *(float4*)(op + 4) = o1;
  }
}

extern "C" void kernel_launch(void* const* d_in, const int* in_sizes, int n_in,
                              void* d_out, int out_size, void* d_ws, size_t ws_size,
                              hipStream_t stream) {
  const float* feats = (const float*)d_in[0];
  const int* src = (const int*)d_in[1];
  const int* dst = (const int*)d_in[2];
  const float* W0 = (const float*)d_in[3];
  const float* b0 = (const float*)d_in[4];
  const float* W1 = (const float*)d_in[5];
  const float* b1 = (const float*)d_in[6];
  const float* W2 = (const float*)d_in[7];
  const float* b2 = (const float*)d_in[8];
  const float* Wo = (const float*)d_in[9];
  const float* bo = (const float*)d_in[10];
  float* out = (float*)d_out;

  const int N = in_sizes[0] / 128;
  const int E = in_sizes[1];
  const int NP = (N + 127) & ~127;
  const int NBK = (N + 255) >> SH;
  const int SCN = NBK * G1;
  const int SCN2 = 2 * SCN;

  char* p = (char*)d_ws;
  auto take = [&](size_t bytes) { char* q = p; p += (bytes + 255) & ~(size_t)255; return q; };
  ushort* xb   = (ushort*)take((size_t)NP * 128 * 2);
  ushort* hbuf = (ushort*)take((size_t)NP * 128 * 2);
  ushort* ybuf = (ushort*)take((size_t)NP * 128 * 2);
  // z region aliases the temporary build arrays: build finishes before
  // layer-2 GEMM first touches zbuf.
  char* zregion = take((size_t)NP * 64 * 4 + (size_t)NP * 64 * 2);
  float*  zbuf = (float*)zregion;
  ushort* zbb  = (ushort*)(zregion + (size_t)NP * 64 * 4);
  uint2* ebuf = (uint2*)zregion;
  uint*  sbuf = (uint*)(zregion + (size_t)E * 8);
  int*   H    = (int*)(zregion + (size_t)E * 8 + (size_t)E * 4);
  int*   H2   = H + SCN2;
  ushort* Wt1 = (ushort*)take((size_t)128 * 128 * 2);
  ushort* Wt2 = (ushort*)take((size_t)192 * 128 * 2);
  ushort* Wt3 = (ushort*)take((size_t)192 * 128 * 2);
  ushort* Wt4 = (ushort*)take((size_t)64 * 128 * 2);
  float* out_norm = (float*)take((size_t)N * 4);
  float* in_norm  = (float*)take((size_t)N * 4);
  int* offsets    = (int*)take((size_t)(N + 1) * 4);
  int* blocksums  = (int*)take(1024);
  int* csr        = (int*)take((size_t)E * 4);
  (void)ws_size; (void)n_in; (void)out_size;

  // ---- graph build (no global atomics) ----
  p1hist<<<G1, 256, 0, stream>>>(src, dst, E, NBK, SCN, H);
  int NBs = (SCN2 + 2047) / 2048;
  scanA<<<NBs, 256, 0, stream>>>(H, SCN2, H2, blocksums);
  scanB<<<1, 256, 0, stream>>>(blocksums, NBs);
  scanC<<<512, 256, 0, stream>>>(H2, blocksums, SCN2);
  p1scatter<<<G1, 256, 0, stream>>>(src, dst, E, NBK, SCN, H2, ebuf, sbuf);
  p2build<<<NBK, 256, 0, stream>>>(ebuf, sbuf, H2, E, N, NBK, SCN,
                                   offsets, csr, out_norm, in_norm);

  // ---- dense prep ----
  prep_w<<<576, 64, 0, stream>>>(W0, W1, W2, Wo, Wt1, Wt2, Wt3, Wt4);
  prep_x<<<2048, 256, 0, stream>>>(feats, (uint*)xb, N * 64);

  dim3 blk(256);
  int rb = NP / 128;
  int ab = (N + 3) / 4;

  gemm_mfma<128, true, 0><<<rb, blk, 0, stream>>>(xb, N, Wt1, ybuf, out_norm, nullptr, nullptr);
  agg_kernel<<<ab, blk, 0, stream>>>(ybuf, (uint*)hbuf, csr, offsets, in_norm, b0, N);
  gemm_mfma<192, true, 1><<<rb, blk, 0, stream>>>(hbuf, N, Wt2, ybuf, out_norm, zbuf, nullptr);
  agg_kernel<<<ab, blk, 0, stream>>>(ybuf, (uint*)hbuf, csr, offsets, in_norm, b1, N);
  gemm_mfma<192, true, 2><<<rb, blk, 0, stream>>>(hbuf, N, Wt3, ybuf, out_norm, zbuf, nullptr);
  agg_kernel<<<ab, blk, 0, stream>>>(ybuf, (uint*)hbuf, csr, offsets, in_norm, b2, N);
  gemm_mfma<64, false, 3><<<rb, blk, 0, stream>>>(hbuf, N, Wt4, nullptr, nullptr, zbuf, zbb);
  pool_kernel<<<ab, blk, 0, stream>>>(zbb, out, csr, offsets, bo, N);
}

// Round 5
// 383.064 us; speedup vs baseline: 2.6403x; 1.0310x over previous
//
#include <hip/hip_runtime.h>

typedef unsigned int uint;
typedef unsigned short ushort;
typedef __bf16 bf16x8 __attribute__((ext_vector_type(8)));
typedef float f32x4 __attribute__((ext_vector_type(4)));

#define G1 512          // pass-1 blocks
#define SH 8            // 256 nodes per coarse bucket

__device__ __forceinline__ ushort f2b(float f) {
  union { float f; uint u; } x; x.f = f;
  uint r = x.u + 0x7fff + ((x.u >> 16) & 1);
  return (ushort)(r >> 16);
}
__device__ __forceinline__ float b2f(uint s) {
  union { uint u; float f; } x; x.u = s << 16;
  return x.f;
}

__device__ __forceinline__ void gload_lds16(const void* g, void* l) {
  __builtin_amdgcn_global_load_lds(
      (const __attribute__((address_space(1))) void*)g,
      (__attribute__((address_space(3))) void*)l, 16, 0, 0);
}

// ---------------- pass 1a: per-(block,bucket) histograms of dst and src ----------------
__global__ void p1hist(const int* __restrict__ src, const int* __restrict__ dst, int E,
                       int NBK, int SCN, int* __restrict__ H) {
  __shared__ int hd[512], hs[512];
  int t = threadIdx.x, b = blockIdx.x;
  hd[t] = 0; hd[t + 256] = 0; hs[t] = 0; hs[t + 256] = 0;
  __syncthreads();
  int chunk = (E + G1 - 1) / G1;
  int c0 = b * chunk, c1 = min(E, c0 + chunk);
  for (int e = c0 + t; e < c1; e += 256) {
    atomicAdd(&hd[dst[e] >> SH], 1);
    atomicAdd(&hs[src[e] >> SH], 1);
  }
  __syncthreads();
  for (int k = t; k < NBK; k += 256) {
    H[k * G1 + b] = hd[k];
    H[SCN + k * G1 + b] = hs[k];
  }
}

// ---------------- scan chain over H (length n) -> H2 exclusive ----------------
__global__ void scanA(const int* __restrict__ in, int n, int* __restrict__ out,
                      int* __restrict__ bsum) {
  __shared__ int sd[256];
  int t = threadIdx.x;
  int base = blockIdx.x * 2048 + t * 8;
  int v[8]; int s = 0;
#pragma unroll
  for (int k = 0; k < 8; ++k) { v[k] = (base + k < n) ? in[base + k] : 0; s += v[k]; }
  sd[t] = s;
  __syncthreads();
  for (int d = 1; d < 256; d <<= 1) {
    int tmp = (t >= d) ? sd[t - d] : 0;
    __syncthreads();
    if (t >= d) sd[t] += tmp;
    __syncthreads();
  }
  int run = sd[t] - s;
#pragma unroll
  for (int k = 0; k < 8; ++k) {
    if (base + k < n) out[base + k] = run;
    run += v[k];
  }
  if (t == 255) bsum[blockIdx.x] = sd[255];
}

__global__ void scanB(int* __restrict__ bsum, int NB_) {
  __shared__ int sd[256];
  int t = threadIdx.x;
  int v = (t < NB_) ? bsum[t] : 0;
  sd[t] = v;
  __syncthreads();
  for (int d = 1; d < 256; d <<= 1) {
    int tmp = (t >= d) ? sd[t - d] : 0;
    __syncthreads();
    if (t >= d) sd[t] += tmp;
    __syncthreads();
  }
  if (t < NB_) bsum[t] = sd[t] - v;
}

__global__ void scanC(int* __restrict__ out, const int* __restrict__ bsum, int n) {
  int stride = gridDim.x * blockDim.x;
  for (int i = blockIdx.x * blockDim.x + threadIdx.x; i < n; i += stride)
    out[i] += bsum[i >> 11];
}

// ---------------- pass 1b: scatter records into coarse buckets ----------------
__global__ void p1scatter(const int* __restrict__ src, const int* __restrict__ dst, int E,
                          int NBK, int SCN, const int* __restrict__ H2,
                          uint2* __restrict__ ebuf, uint* __restrict__ sbuf) {
  __shared__ int cd[512], cs[512];
  int t = threadIdx.x, b = blockIdx.x;
  for (int k = t; k < NBK; k += 256) {
    cd[k] = H2[k * G1 + b];
    cs[k] = H2[SCN + k * G1 + b] - E;
  }
  __syncthreads();
  int chunk = (E + G1 - 1) / G1;
  int c0 = b * chunk, c1 = min(E, c0 + chunk);
  for (int e = c0 + t; e < c1; e += 256) {
    int d = dst[e], s = src[e];
    int p = atomicAdd(&cd[d >> SH], 1);
    ebuf[p] = make_uint2((uint)d, (uint)s);
    int q = atomicAdd(&cs[s >> SH], 1);
    sbuf[q] = (uint)s;
  }
}

// ---------------- pass 2: per-bucket fine CSR + degrees/norms ----------------
__global__ void p2build(const uint2* __restrict__ ebuf, const uint* __restrict__ sbuf,
                        const int* __restrict__ H2, int E, int N, int NBK, int SCN,
                        int* __restrict__ offsets, int* __restrict__ csr,
                        float* __restrict__ out_norm, float* __restrict__ in_norm) {
  __shared__ int cnt[256], sd[256], cur[256];
  int t = threadIdx.x, buck = blockIdx.x;
  int base = buck << SH;
  int dbase = H2[buck * G1];
  int dend = (buck == NBK - 1) ? E : H2[(buck + 1) * G1];
  int sbase = H2[SCN + buck * G1] - E;
  int send = (buck == NBK - 1) ? E : (H2[SCN + (buck + 1) * G1] - E);

  cnt[t] = 0;
  __syncthreads();
  for (int i = sbase + t; i < send; i += 256) atomicAdd(&cnt[sbuf[i] & 255], 1);
  __syncthreads();
  if (base + t < N) out_norm[base + t] = cnt[t] > 0 ? rsqrtf((float)cnt[t]) : 0.f;
  __syncthreads();

  cnt[t] = 0;
  __syncthreads();
  for (int i = dbase + t; i < dend; i += 256) atomicAdd(&cnt[ebuf[i].x & 255], 1);
  __syncthreads();
  int v = cnt[t];
  sd[t] = v;
  __syncthreads();
  for (int d = 1; d < 256; d <<= 1) {
    int tmp = (t >= d) ? sd[t - d] : 0;
    __syncthreads();
    if (t >= d) sd[t] += tmp;
    __syncthreads();
  }
  int excl = sd[t] - v;
  if (base + t < N) {
    offsets[base + t] = dbase + excl;
    in_norm[base + t] = v > 0 ? rsqrtf((float)v) : 0.f;
  }
  if (buck == NBK - 1 && t == 0) offsets[N] = E;
  cur[t] = dbase + excl;
  __syncthreads();
  for (int i = dbase + t; i < dend; i += 256) {
    uint2 r = ebuf[i];
    int p = atomicAdd(&cur[r.x & 255], 1);
    csr[p] = (int)r.y;
  }
}

// ---------------- prep: feats fp32 -> bf16 swizzled rows (16B stores) ----------------
__global__ void prep_x(const float* __restrict__ feats, uint4* __restrict__ xb, int total16) {
  int stride = gridDim.x * blockDim.x;
  for (int i = blockIdx.x * blockDim.x + threadIdx.x; i < total16; i += stride) {
    int node = i >> 4, q = i & 15;
    const float* fp = feats + (size_t)node * 128 + q * 8;
    float4 f0 = *(const float4*)fp;
    float4 f1 = *(const float4*)(fp + 4);
    uint4 o;
    o.x = (uint)f2b(f0.x) | ((uint)f2b(f0.y) << 16);
    o.y = (uint)f2b(f0.z) | ((uint)f2b(f0.w) << 16);
    o.z = (uint)f2b(f1.x) | ((uint)f2b(f1.y) << 16);
    o.w = (uint)f2b(f1.z) | ((uint)f2b(f1.w) << 16);
    xb[(size_t)node * 16 + (q ^ (node & 7))] = o;
  }
}

// ---------------- prep: weights -> bf16 [n][k] transposed, swizzled ----------------
__global__ void prep_w(const float* __restrict__ W0, const float* __restrict__ W1,
                       const float* __restrict__ W2, const float* __restrict__ Wo,
                       ushort* __restrict__ Wt1, ushort* __restrict__ Wt2,
                       ushort* __restrict__ Wt3, ushort* __restrict__ Wt4) {
  int rid = blockIdx.x;   // 0..575
  int t = threadIdx.x;    // 0..63
  ushort* dst; const float* srcbase; int srcstride; int row;
  if (rid < 128)      { dst = Wt1; row = rid;        srcbase = W0 + row; srcstride = 128; }
  else if (rid < 320) { dst = Wt2; row = rid - 128;
    if (row < 128) { srcbase = W1 + row; srcstride = 128; }
    else           { srcbase = Wo + (row - 128); srcstride = 64; } }
  else if (rid < 512) { dst = Wt3; row = rid - 320;
    if (row < 128) { srcbase = W2 + row; srcstride = 128; }
    else           { srcbase = Wo + 128 * 64 + (row - 128); srcstride = 64; } }
  else                { dst = Wt4; row = rid - 512; srcbase = Wo + 256 * 64 + row; srcstride = 64; }
#pragma unroll
  for (int kk = 0; kk < 2; ++kk) {
    int k = t + kk * 64;
    float v = srcbase[(size_t)k * srcstride];
    dst[row * 128 + (k ^ ((row & 7) << 3))] = f2b(v);
  }
}

// ---------------- MFMA GEMM: A direct global->reg, B-only LDS, one barrier ----------------
template <int NB, bool HASY, int ZMODE>
__global__ __launch_bounds__(256)
void gemm_mfma(const ushort* __restrict__ xb, int N,
               const ushort* __restrict__ wt,
               ushort* __restrict__ y, const float* __restrict__ onorm,
               float* __restrict__ z, ushort* __restrict__ zb) {
  constexpr int NT = NB / 16;
  __shared__ ushort Bs[NB * 128];
  const int tid = threadIdx.x;
  const int row0 = blockIdx.x * 128;
  const int w = tid >> 6, l = tid & 63;
  const int lr = l & 15, lg = l >> 4;

  // A fragments: direct global loads (issued before barrier, overlap B staging).
  // Swizzle is baked into the stored layout; fold it into the address.
  bf16x8 a[2][4];
#pragma unroll
  for (int mt = 0; mt < 2; ++mt)
#pragma unroll
    for (int kk = 0; kk < 4; ++kk) {
      int row = row0 + w * 32 + mt * 16 + lr;
      int idx = (row * 128 + kk * 32 + lg * 8) ^ ((row & 7) << 3);
      a[mt][kk] = *(const bf16x8*)&xb[idx];
    }

#pragma unroll
  for (int it = 0; it < NB / 16; ++it)
    gload_lds16(wt + it * 2048 + tid * 8, &Bs[it * 2048 + tid * 8]);
  __syncthreads();

  f32x4 acc[2][NT];
#pragma unroll
  for (int mt = 0; mt < 2; ++mt)
#pragma unroll
    for (int nt = 0; nt < NT; ++nt) acc[mt][nt] = (f32x4)0.f;

#pragma unroll
  for (int nt = 0; nt < NT; ++nt) {
    bf16x8 b[4];
#pragma unroll
    for (int kk = 0; kk < 4; ++kk) {
      int row = nt * 16 + lr;
      int idx = (row * 128 + kk * 32 + lg * 8) ^ ((row & 7) << 3);
      b[kk] = *(const bf16x8*)&Bs[idx];
    }
#pragma unroll
    for (int mt = 0; mt < 2; ++mt)
#pragma unroll
      for (int kk = 0; kk < 4; ++kk)
        acc[mt][nt] = __builtin_amdgcn_mfma_f32_16x16x32_bf16(a[mt][kk], b[kk], acc[mt][nt], 0, 0, 0);
  }

  float norms[2][4];
  if (HASY) {
#pragma unroll
    for (int mt = 0; mt < 2; ++mt)
#pragma unroll
      for (int j = 0; j < 4; ++j) {
        int r = row0 + w * 32 + mt * 16 + lg * 4 + j;
        norms[mt][j] = (r < N) ? onorm[r] : 0.f;
      }
  }

#pragma unroll
  for (int mt = 0; mt < 2; ++mt)
#pragma unroll
    for (int j = 0; j < 4; ++j) {
      int r = row0 + w * 32 + mt * 16 + lg * 4 + j;
      if (r >= N) continue;
#pragma unroll
      for (int nt = 0; nt < NT; ++nt) {
        int c = nt * 16 + lr;
        float v = acc[mt][nt][j];
        if (HASY && c < 128) {
          y[r * 128 + c] = f2b(v * norms[mt][j]);
        } else {
          int zc = c - (HASY ? 128 : 0);
          if (ZMODE == 1) z[r * 64 + zc] = v;
          else if (ZMODE == 2) z[r * 64 + zc] += v;
          else if (ZMODE == 3) zb[r * 64 + zc] = f2b(z[r * 64 + zc] + v);
        }
      }
    }
}

// ---------------- aggregation (vectorized gather, 16-deep): one wave per node ----------------
#define ACC8(v)                                              \
  a[0] += b2f(v.x & 0xffff); a[1] += b2f(v.x >> 16);         \
  a[2] += b2f(v.y & 0xffff); a[3] += b2f(v.y >> 16);         \
  a[4] += b2f(v.z & 0xffff); a[5] += b2f(v.z >> 16);         \
  a[6] += b2f(v.w & 0xffff); a[7] += b2f(v.w >> 16);

__global__ void agg_kernel(const ushort* __restrict__ y, uint* __restrict__ h,
                           const int* __restrict__ csr, const int* __restrict__ offsets,
                           const float* __restrict__ in_norm, const float* __restrict__ bias,
                           int N) {
  int node = blockIdx.x * 4 + (threadIdx.x >> 6);
  if (node >= N) return;
  const int l = threadIdx.x & 63;
  const int g = l >> 4;
  const int q = l & 15;
  const uint4* yp = (const uint4*)y;   // 16 uint4 per row
  int off = offsets[node], end = offsets[node + 1];
  float a[8];
#pragma unroll
  for (int k = 0; k < 8; ++k) a[k] = 0.f;

  int i = off;
  for (; i + 16 <= end; i += 16) {
    int s0 = csr[i + g];
    int s1 = csr[i + 4 + g];
    int s2 = csr[i + 8 + g];
    int s3 = csr[i + 12 + g];
    uint4 v0 = yp[(size_t)s0 * 16 + q];
    uint4 v1 = yp[(size_t)s1 * 16 + q];
    uint4 v2 = yp[(size_t)s2 * 16 + q];
    uint4 v3 = yp[(size_t)s3 * 16 + q];
    ACC8(v0) ACC8(v1) ACC8(v2) ACC8(v3)
  }
  if (i + 8 <= end) {
    int s0 = csr[i + g];
    int s1 = csr[i + 4 + g];
    uint4 v0 = yp[(size_t)s0 * 16 + q];
    uint4 v1 = yp[(size_t)s1 * 16 + q];
    ACC8(v0) ACC8(v1)
    i += 8;
  }
  if (i + 4 <= end) {
    int s0 = csr[i + g];
    uint4 v0 = yp[(size_t)s0 * 16 + q];
    ACC8(v0)
    i += 4;
  }
  if (i < end) {
    bool valid = (i + g) < end;
    int s0 = csr[valid ? (i + g) : (end - 1)];
    uint4 v0 = yp[(size_t)s0 * 16 + q];
    if (valid) { ACC8(v0) }
  }
#pragma unroll
  for (int k = 0; k < 8; ++k) {
    a[k] += __shfl_xor(a[k], 16);
    a[k] += __shfl_xor(a[k], 32);
  }
  if (g == 0) {
    float s = in_norm[node];
    float4 b0 = *(const float4*)(bias + 8 * q);
    float4 b1 = *(const float4*)(bias + 8 * q + 4);
    float r0 = fmaxf(fmaf(a[0], s, b0.x), 0.f);
    float r1 = fmaxf(fmaf(a[1], s, b0.y), 0.f);
    float r2 = fmaxf(fmaf(a[2], s, b0.z), 0.f);
    float r3 = fmaxf(fmaf(a[3], s, b0.w), 0.f);
    float r4 = fmaxf(fmaf(a[4], s, b1.x), 0.f);
    float r5 = fmaxf(fmaf(a[5], s, b1.y), 0.f);
    float r6 = fmaxf(fmaf(a[6], s, b1.z), 0.f);
    float r7 = fmaxf(fmaf(a[7], s, b1.w), 0.f);
    uint4 o;
    o.x = (uint)f2b(r0) | ((uint)f2b(r1) << 16);
    o.y = (uint)f2b(r2) | ((uint)f2b(r3) << 16);
    o.z = (uint)f2b(r4) | ((uint)f2b(r5) << 16);
    o.w = (uint)f2b(r6) | ((uint)f2b(r7) << 16);
    ((uint4*)h)[(size_t)node * 16 + (q ^ (node & 7))] = o;
  }
}

// ---------------- pooling (vectorized gather, 16-deep): one wave per node ----------------
__global__ void pool_kernel(const ushort* __restrict__ zb, float* __restrict__ out,
                            const int* __restrict__ csr, const int* __restrict__ offsets,
                            const float* __restrict__ bo, int N) {
  int node = blockIdx.x * 4 + (threadIdx.x >> 6);
  if (node >= N) return;
  const int l = threadIdx.x & 63;
  const int g = l >> 3;
  const int p = l & 7;
  const uint4* zp = (const uint4*)zb;  // 8 uint4 per row
  int off = offsets[node], end = offsets[node + 1];
  float a[8];
#pragma unroll
  for (int k = 0; k < 8; ++k) a[k] = 0.f;

  int i = off;
  for (; i + 16 <= end; i += 16) {
    int s0 = csr[i + g];
    int s1 = csr[i + 8 + g];
    uint4 v0 = zp[(size_t)s0 * 8 + p];
    uint4 v1 = zp[(size_t)s1 * 8 + p];
    ACC8(v0) ACC8(v1)
  }
  if (i + 8 <= end) {
    int s0 = csr[i + g];
    uint4 v0 = zp[(size_t)s0 * 8 + p];
    ACC8(v0)
    i += 8;
  }
  if (i < end) {
    bool valid = (i + g) < end;
    int s0 = csr[valid ? (i + g) : (end - 1)];
    uint4 v0 = zp[(size_t)s0 * 8 + p];
    if (valid) { ACC8(v0) }
  }
#pragma unroll
  for (int k = 0; k < 8; ++k) {
    a[k] += __shfl_xor(a[k], 8);
    a[k] += __shfl_xor(a[k], 16);
    a[k] += __shfl_xor(a[k], 32);
  }
  if (g == 0) {
    float4 o0, o1;
    o0.x = a[0] + bo[8 * p + 0];
    o0.y = a[1] + bo[8 * p + 1];
    o0.z = a[2] + bo[8 * p + 2];
    o0.w = a[3] + bo[8 * p + 3];
    o1.x = a[4] + bo[8 * p + 4];
    o1.y = a[5] + bo[8 * p + 5];
    o1.z = a[6] + bo[8 * p + 6];
    o1.w = a[7] + bo[8 * p + 7];
    float* op = out + (size_t)node * 64 + 8 * p;
    *(float4*)op = o0;
    *(float4*)(op + 4) = o1;
  }
}

extern "C" void kernel_launch(void* const* d_in, const int* in_sizes, int n_in,
                              void* d_out, int out_size, void* d_ws, size_t ws_size,
                              hipStream_t stream) {
  const float* feats = (const float*)d_in[0];
  const int* src = (const int*)d_in[1];
  const int* dst = (const int*)d_in[2];
  const float* W0 = (const float*)d_in[3];
  const float* b0 = (const float*)d_in[4];
  const float* W1 = (const float*)d_in[5];
  const float* b1 = (const float*)d_in[6];
  const float* W2 = (const float*)d_in[7];
  const float* b2 = (const float*)d_in[8];
  const float* Wo = (const float*)d_in[9];
  const float* bo = (const float*)d_in[10];
  float* out = (float*)d_out;

  const int N = in_sizes[0] / 128;
  const int E = in_sizes[1];
  const int NP = (N + 127) & ~127;
  const int NBK = (N + 255) >> SH;
  const int SCN = NBK * G1;
  const int SCN2 = 2 * SCN;

  char* p = (char*)d_ws;
  auto take = [&](size_t bytes) { char* q = p; p += (bytes + 255) & ~(size_t)255; return q; };
  ushort* xb   = (ushort*)take((size_t)NP * 128 * 2);
  ushort* hbuf = (ushort*)take((size_t)NP * 128 * 2);
  ushort* ybuf = (ushort*)take((size_t)NP * 128 * 2);
  // z region aliases the temporary build arrays: build finishes before
  // layer-2 GEMM first touches zbuf.
  char* zregion = take((size_t)NP * 64 * 4 + (size_t)NP * 64 * 2);
  float*  zbuf = (float*)zregion;
  ushort* zbb  = (ushort*)(zregion + (size_t)NP * 64 * 4);
  uint2* ebuf = (uint2*)zregion;
  uint*  sbuf = (uint*)(zregion + (size_t)E * 8);
  int*   H    = (int*)(zregion + (size_t)E * 8 + (size_t)E * 4);
  int*   H2   = H + SCN2;
  ushort* Wt1 = (ushort*)take((size_t)128 * 128 * 2);
  ushort* Wt2 = (ushort*)take((size_t)192 * 128 * 2);
  ushort* Wt3 = (ushort*)take((size_t)192 * 128 * 2);
  ushort* Wt4 = (ushort*)take((size_t)64 * 128 * 2);
  float* out_norm = (float*)take((size_t)N * 4);
  float* in_norm  = (float*)take((size_t)N * 4);
  int* offsets    = (int*)take((size_t)(N + 1) * 4);
  int* blocksums  = (int*)take(1024);
  int* csr        = (int*)take((size_t)E * 4);
  (void)ws_size; (void)n_in; (void)out_size;

  // ---- graph build (no global atomics) ----
  p1hist<<<G1, 256, 0, stream>>>(src, dst, E, NBK, SCN, H);
  int NBs = (SCN2 + 2047) / 2048;
  scanA<<<NBs, 256, 0, stream>>>(H, SCN2, H2, blocksums);
  scanB<<<1, 256, 0, stream>>>(blocksums, NBs);
  scanC<<<512, 256, 0, stream>>>(H2, blocksums, SCN2);
  p1scatter<<<G1, 256, 0, stream>>>(src, dst, E, NBK, SCN, H2, ebuf, sbuf);
  p2build<<<NBK, 256, 0, stream>>>(ebuf, sbuf, H2, E, N, NBK, SCN,
                                   offsets, csr, out_norm, in_norm);

  // ---- dense prep ----
  prep_w<<<576, 64, 0, stream>>>(W0, W1, W2, Wo, Wt1, Wt2, Wt3, Wt4);
  prep_x<<<1024, 256, 0, stream>>>(feats, (uint4*)xb, N * 16);

  dim3 blk(256);
  int rb = NP / 128;
  int ab = (N + 3) / 4;

  gemm_mfma<128, true, 0><<<rb, blk, 0, stream>>>(xb, N, Wt1, ybuf, out_norm, nullptr, nullptr);
  agg_kernel<<<ab, blk, 0, stream>>>(ybuf, (uint*)hbuf, csr, offsets, in_norm, b0, N);
  gemm_mfma<192, true, 1><<<rb, blk, 0, stream>>>(hbuf, N, Wt2, ybuf, out_norm, zbuf, nullptr);
  agg_kernel<<<ab, blk, 0, stream>>>(ybuf, (uint*)hbuf, csr, offsets, in_norm, b1, N);
  gemm_mfma<192, true, 2><<<rb, blk, 0, stream>>>(hbuf, N, Wt3, ybuf, out_norm, zbuf, nullptr);
  agg_kernel<<<ab, blk, 0, stream>>>(ybuf, (uint*)hbuf, csr, offsets, in_norm, b2, N);
  gemm_mfma<64, false, 3><<<rb, blk, 0, stream>>>(hbuf, N, Wt4, nullptr, nullptr, zbuf, zbb);
  pool_kernel<<<ab, blk, 0, stream>>>(zbb, out, csr, offsets, bo, N);
}

// Round 6
// 372.481 us; speedup vs baseline: 2.7153x; 1.0284x over previous
//
#include <hip/hip_runtime.h>

typedef unsigned int uint;
typedef unsigned short ushort;
typedef unsigned char uchar;
typedef __bf16 bf16x8 __attribute__((ext_vector_type(8)));
typedef float f32x4 __attribute__((ext_vector_type(4)));
typedef float f32x2 __attribute__((ext_vector_type(2)));

#define G1 512          // pass-1 blocks
#define SH 8            // 256 nodes per coarse bucket

__device__ __forceinline__ ushort f2b(float f) {
  union { float f; uint u; } x; x.f = f;
  uint r = x.u + 0x7fff + ((x.u >> 16) & 1);
  return (ushort)(r >> 16);
}

// unpack 2 bf16 packed in a uint -> float2 (1 VALU op per channel)
__device__ __forceinline__ f32x2 up2(uint u) {
  union { uint u; float f; } lo, hi;
  lo.u = u << 16;
  hi.u = u & 0xffff0000u;
  f32x2 r; r.x = lo.f; r.y = hi.f;
  return r;
}

__device__ __forceinline__ void gload_lds16(const void* g, void* l) {
  __builtin_amdgcn_global_load_lds(
      (const __attribute__((address_space(1))) void*)g,
      (__attribute__((address_space(3))) void*)l, 16, 0, 0);
}

// ---------------- pass 1a: per-(block,bucket) histograms of dst and src ----------------
__global__ void p1hist(const int* __restrict__ src, const int* __restrict__ dst, int E,
                       int NBK, int SCN, int* __restrict__ H) {
  __shared__ int hd[512], hs[512];
  int t = threadIdx.x, b = blockIdx.x;
  hd[t] = 0; hd[t + 256] = 0; hs[t] = 0; hs[t + 256] = 0;
  __syncthreads();
  int chunk = (E + G1 - 1) / G1;
  int c0 = b * chunk, c1 = min(E, c0 + chunk);
  for (int e = c0 + t; e < c1; e += 256) {
    atomicAdd(&hd[dst[e] >> SH], 1);
    atomicAdd(&hs[src[e] >> SH], 1);
  }
  __syncthreads();
  for (int k = t; k < NBK; k += 256) {
    H[k * G1 + b] = hd[k];
    H[SCN + k * G1 + b] = hs[k];
  }
}

// ---------------- scan chain over H (length n) -> H2 exclusive ----------------
__global__ void scanA(const int* __restrict__ in, int n, int* __restrict__ out,
                      int* __restrict__ bsum) {
  __shared__ int sd[256];
  int t = threadIdx.x;
  int base = blockIdx.x * 2048 + t * 8;
  int v[8]; int s = 0;
#pragma unroll
  for (int k = 0; k < 8; ++k) { v[k] = (base + k < n) ? in[base + k] : 0; s += v[k]; }
  sd[t] = s;
  __syncthreads();
  for (int d = 1; d < 256; d <<= 1) {
    int tmp = (t >= d) ? sd[t - d] : 0;
    __syncthreads();
    if (t >= d) sd[t] += tmp;
    __syncthreads();
  }
  int run = sd[t] - s;
#pragma unroll
  for (int k = 0; k < 8; ++k) {
    if (base + k < n) out[base + k] = run;
    run += v[k];
  }
  if (t == 255) bsum[blockIdx.x] = sd[255];
}

__global__ void scanB(int* __restrict__ bsum, int NB_) {
  __shared__ int sd[256];
  int t = threadIdx.x;
  int v = (t < NB_) ? bsum[t] : 0;
  sd[t] = v;
  __syncthreads();
  for (int d = 1; d < 256; d <<= 1) {
    int tmp = (t >= d) ? sd[t - d] : 0;
    __syncthreads();
    if (t >= d) sd[t] += tmp;
    __syncthreads();
  }
  if (t < NB_) bsum[t] = sd[t] - v;
}

__global__ void scanC(int* __restrict__ out, const int* __restrict__ bsum, int n) {
  int stride = gridDim.x * blockDim.x;
  for (int i = blockIdx.x * blockDim.x + threadIdx.x; i < n; i += stride)
    out[i] += bsum[i >> 11];
}

// ---------------- pass 1b: scatter packed records into coarse buckets ----------------
// ebuf entry: (src << 8) | (dst & 255)    sbuf entry: src & 255 (byte)
__global__ void p1scatter(const int* __restrict__ src, const int* __restrict__ dst, int E,
                          int NBK, int SCN, const int* __restrict__ H2,
                          uint* __restrict__ ebuf, uchar* __restrict__ sbuf) {
  __shared__ int cd[512], cs[512];
  int t = threadIdx.x, b = blockIdx.x;
  for (int k = t; k < NBK; k += 256) {
    cd[k] = H2[k * G1 + b];
    cs[k] = H2[SCN + k * G1 + b] - E;
  }
  __syncthreads();
  int chunk = (E + G1 - 1) / G1;
  int c0 = b * chunk, c1 = min(E, c0 + chunk);
  for (int e = c0 + t; e < c1; e += 256) {
    int d = dst[e], s = src[e];
    int p = atomicAdd(&cd[d >> SH], 1);
    ebuf[p] = ((uint)s << 8) | (uint)(d & 255);
    int q = atomicAdd(&cs[s >> SH], 1);
    sbuf[q] = (uchar)(s & 255);
  }
}

// ---------------- pass 2: per-bucket fine CSR + degrees/norms ----------------
__global__ void p2build(const uint* __restrict__ ebuf, const uchar* __restrict__ sbuf,
                        const int* __restrict__ H2, int E, int N, int NBK, int SCN,
                        int* __restrict__ offsets, int* __restrict__ csr,
                        float* __restrict__ out_norm, float* __restrict__ in_norm) {
  __shared__ int cnt[256], sd[256], cur[256];
  int t = threadIdx.x, buck = blockIdx.x;
  int base = buck << SH;
  int dbase = H2[buck * G1];
  int dend = (buck == NBK - 1) ? E : H2[(buck + 1) * G1];
  int sbase = H2[SCN + buck * G1] - E;
  int send = (buck == NBK - 1) ? E : (H2[SCN + (buck + 1) * G1] - E);

  cnt[t] = 0;
  __syncthreads();
  for (int i = sbase + t; i < send; i += 256) atomicAdd(&cnt[sbuf[i]], 1);
  __syncthreads();
  if (base + t < N) out_norm[base + t] = cnt[t] > 0 ? rsqrtf((float)cnt[t]) : 0.f;
  __syncthreads();

  cnt[t] = 0;
  __syncthreads();
  for (int i = dbase + t; i < dend; i += 256) atomicAdd(&cnt[ebuf[i] & 255u], 1);
  __syncthreads();
  int v = cnt[t];
  sd[t] = v;
  __syncthreads();
  for (int d = 1; d < 256; d <<= 1) {
    int tmp = (t >= d) ? sd[t - d] : 0;
    __syncthreads();
    if (t >= d) sd[t] += tmp;
    __syncthreads();
  }
  int excl = sd[t] - v;
  if (base + t < N) {
    offsets[base + t] = dbase + excl;
    in_norm[base + t] = v > 0 ? rsqrtf((float)v) : 0.f;
  }
  if (buck == NBK - 1 && t == 0) offsets[N] = E;
  cur[t] = dbase + excl;
  __syncthreads();
  for (int i = dbase + t; i < dend; i += 256) {
    uint r = ebuf[i];
    int p = atomicAdd(&cur[r & 255u], 1);
    csr[p] = (int)(r >> 8);
  }
}

// ---------------- prep: feats fp32 -> bf16 rows (linear, 16B stores) ----------------
__global__ void prep_x(const float* __restrict__ feats, uint4* __restrict__ xb, int total16) {
  int stride = gridDim.x * blockDim.x;
  for (int i = blockIdx.x * blockDim.x + threadIdx.x; i < total16; i += stride) {
    const float* fp = feats + (size_t)i * 8;
    float4 f0 = *(const float4*)fp;
    float4 f1 = *(const float4*)(fp + 4);
    uint4 o;
    o.x = (uint)f2b(f0.x) | ((uint)f2b(f0.y) << 16);
    o.y = (uint)f2b(f0.z) | ((uint)f2b(f0.w) << 16);
    o.z = (uint)f2b(f1.x) | ((uint)f2b(f1.y) << 16);
    o.w = (uint)f2b(f1.z) | ((uint)f2b(f1.w) << 16);
    xb[i] = o;
  }
}

// ---------------- prep: weights -> bf16 [n][k] transposed, k-swizzled ----------------
// Wt1/2/3: [128][128] from W0/W1/W2.  Wz: [64][384] from Wo (K=384 concat).
__global__ void prep_w(const float* __restrict__ W0, const float* __restrict__ W1,
                       const float* __restrict__ W2, const float* __restrict__ Wo,
                       ushort* __restrict__ Wt1, ushort* __restrict__ Wt2,
                       ushort* __restrict__ Wt3, ushort* __restrict__ Wz) {
  int rid = blockIdx.x;   // 0..447
  int t = threadIdx.x;    // 0..63
  if (rid < 384) {
    ushort* dst; const float* W; int row;
    if (rid < 128)      { dst = Wt1; W = W0; row = rid; }
    else if (rid < 256) { dst = Wt2; W = W1; row = rid - 128; }
    else                { dst = Wt3; W = W2; row = rid - 256; }
#pragma unroll
    for (int kk = 0; kk < 2; ++kk) {
      int k = t + kk * 64;
      dst[row * 128 + (k ^ ((row & 7) << 3))] = f2b(W[(size_t)k * 128 + row]);
    }
  } else {
    int row = rid - 384;  // 0..63
#pragma unroll
    for (int kk = 0; kk < 6; ++kk) {
      int k = t + kk * 64;
      Wz[row * 384 + (k ^ ((row & 7) << 3))] = f2b(Wo[(size_t)k * 64 + row]);
    }
  }
}

// ---------------- layer GEMM: y = diag(norm)*(x@W), 128 cols, K=128 ----------------
__global__ __launch_bounds__(256)
void gemm_layer(const ushort* __restrict__ xb, int N,
                const ushort* __restrict__ wt,
                ushort* __restrict__ y, const float* __restrict__ onorm) {
  __shared__ ushort Bs[128 * 128];
  const int tid = threadIdx.x;
  const int row0 = blockIdx.x * 128;
  const int w = tid >> 6, l = tid & 63;
  const int lr = l & 15, lg = l >> 4;

  // A: direct global->reg (issued before B staging, overlaps)
  bf16x8 a[2][4];
#pragma unroll
  for (int mt = 0; mt < 2; ++mt)
#pragma unroll
    for (int kk = 0; kk < 4; ++kk) {
      int row = row0 + w * 32 + mt * 16 + lr;
      a[mt][kk] = *(const bf16x8*)&xb[(size_t)row * 128 + kk * 32 + lg * 8];
    }

#pragma unroll
  for (int it = 0; it < 8; ++it)
    gload_lds16(wt + it * 2048 + tid * 8, &Bs[it * 2048 + tid * 8]);
  __syncthreads();

  f32x4 acc[2][8];
#pragma unroll
  for (int mt = 0; mt < 2; ++mt)
#pragma unroll
    for (int nt = 0; nt < 8; ++nt) acc[mt][nt] = (f32x4)0.f;

#pragma unroll
  for (int nt = 0; nt < 8; ++nt) {
    bf16x8 b[4];
#pragma unroll
    for (int kk = 0; kk < 4; ++kk) {
      int row = nt * 16 + lr;
      b[kk] = *(const bf16x8*)&Bs[row * 128 + ((kk * 32 + lg * 8) ^ ((row & 7) << 3))];
    }
#pragma unroll
    for (int mt = 0; mt < 2; ++mt)
#pragma unroll
      for (int kk = 0; kk < 4; ++kk)
        acc[mt][nt] = __builtin_amdgcn_mfma_f32_16x16x32_bf16(a[mt][kk], b[kk], acc[mt][nt], 0, 0, 0);
  }

#pragma unroll
  for (int mt = 0; mt < 2; ++mt)
#pragma unroll
    for (int j = 0; j < 4; ++j) {
      int r = row0 + w * 32 + mt * 16 + lg * 4 + j;
      if (r >= N) continue;
      float s = onorm[r];
#pragma unroll
      for (int nt = 0; nt < 8; ++nt)
        y[(size_t)r * 128 + nt * 16 + lr] = f2b(acc[mt][nt][j] * s);
    }
}

// ---------------- z GEMM: zbb = bf16([h1|h2|h3] @ Wo), K=384, 64 cols ----------------
__global__ __launch_bounds__(256)
void gemm_z(const ushort* __restrict__ h1, const ushort* __restrict__ h2,
            const ushort* __restrict__ h3, int N,
            const ushort* __restrict__ wz, ushort* __restrict__ zbb) {
  __shared__ ushort Bs[64 * 384];
  const int tid = threadIdx.x;
  const int row0 = blockIdx.x * 128;
  const int w = tid >> 6, l = tid & 63;
  const int lr = l & 15, lg = l >> 4;

  bf16x8 a[2][12];
#pragma unroll
  for (int kk = 0; kk < 12; ++kk) {
    const ushort* hp = (kk < 4) ? h1 : (kk < 8) ? h2 : h3;
    int ko = (kk & 3) * 32 + lg * 8;
#pragma unroll
    for (int mt = 0; mt < 2; ++mt) {
      int row = row0 + w * 32 + mt * 16 + lr;
      a[mt][kk] = *(const bf16x8*)&hp[(size_t)row * 128 + ko];
    }
  }

#pragma unroll
  for (int it = 0; it < 12; ++it)
    gload_lds16(wz + it * 2048 + tid * 8, &Bs[it * 2048 + tid * 8]);
  __syncthreads();

  f32x4 acc[2][4];
#pragma unroll
  for (int mt = 0; mt < 2; ++mt)
#pragma unroll
    for (int nt = 0; nt < 4; ++nt) acc[mt][nt] = (f32x4)0.f;

#pragma unroll
  for (int nt = 0; nt < 4; ++nt) {
    int row = nt * 16 + lr;
    int rs = (row & 7) << 3;
#pragma unroll
    for (int kk = 0; kk < 12; ++kk) {
      bf16x8 b = *(const bf16x8*)&Bs[row * 384 + ((kk * 32 + lg * 8) ^ rs)];
#pragma unroll
      for (int mt = 0; mt < 2; ++mt)
        acc[mt][nt] = __builtin_amdgcn_mfma_f32_16x16x32_bf16(a[mt][kk], b, acc[mt][nt], 0, 0, 0);
    }
  }

#pragma unroll
  for (int mt = 0; mt < 2; ++mt)
#pragma unroll
    for (int j = 0; j < 4; ++j) {
      int r = row0 + w * 32 + mt * 16 + lg * 4 + j;
      if (r >= N) continue;
#pragma unroll
      for (int nt = 0; nt < 4; ++nt)
        zbb[(size_t)r * 64 + nt * 16 + lr] = f2b(acc[mt][nt][j]);
    }
}

// ---------------- aggregation (vectorized gather + pk_add): one wave per node ----------------
#define ACCV(v) { a2[0] += up2(v.x); a2[1] += up2(v.y); a2[2] += up2(v.z); a2[3] += up2(v.w); }

__global__ void agg_kernel(const ushort* __restrict__ y, uint* __restrict__ h,
                           const int* __restrict__ csr, const int* __restrict__ offsets,
                           const float* __restrict__ in_norm, const float* __restrict__ bias,
                           int N) {
  int node = blockIdx.x * 4 + (threadIdx.x >> 6);
  if (node >= N) return;
  const int l = threadIdx.x & 63;
  const int g = l >> 4;
  const int q = l & 15;
  const uint4* yp = (const uint4*)y;   // 16 uint4 per row
  int off = offsets[node], end = offsets[node + 1];
  f32x2 a2[4];
#pragma unroll
  for (int k = 0; k < 4; ++k) a2[k] = (f32x2)0.f;

  int i = off;
  for (; i + 16 <= end; i += 16) {
    int s0 = csr[i + g];
    int s1 = csr[i + 4 + g];
    int s2 = csr[i + 8 + g];
    int s3 = csr[i + 12 + g];
    uint4 v0 = yp[(size_t)s0 * 16 + q];
    uint4 v1 = yp[(size_t)s1 * 16 + q];
    uint4 v2 = yp[(size_t)s2 * 16 + q];
    uint4 v3 = yp[(size_t)s3 * 16 + q];
    ACCV(v0) ACCV(v1) ACCV(v2) ACCV(v3)
  }
  if (i + 8 <= end) {
    int s0 = csr[i + g];
    int s1 = csr[i + 4 + g];
    uint4 v0 = yp[(size_t)s0 * 16 + q];
    uint4 v1 = yp[(size_t)s1 * 16 + q];
    ACCV(v0) ACCV(v1)
    i += 8;
  }
  if (i + 4 <= end) {
    int s0 = csr[i + g];
    uint4 v0 = yp[(size_t)s0 * 16 + q];
    ACCV(v0)
    i += 4;
  }
  if (i < end) {
    bool valid = (i + g) < end;
    int s0 = csr[valid ? (i + g) : (end - 1)];
    uint4 v0 = yp[(size_t)s0 * 16 + q];
    if (valid) { ACCV(v0) }
  }
#pragma unroll
  for (int k = 0; k < 4; ++k) {
    a2[k].x += __shfl_xor(a2[k].x, 16);
    a2[k].y += __shfl_xor(a2[k].y, 16);
    a2[k].x += __shfl_xor(a2[k].x, 32);
    a2[k].y += __shfl_xor(a2[k].y, 32);
  }
  if (g == 0) {
    float s = in_norm[node];
    float4 b0 = *(const float4*)(bias + 8 * q);
    float4 b1 = *(const float4*)(bias + 8 * q + 4);
    float r0 = fmaxf(fmaf(a2[0].x, s, b0.x), 0.f);
    float r1 = fmaxf(fmaf(a2[0].y, s, b0.y), 0.f);
    float r2 = fmaxf(fmaf(a2[1].x, s, b0.z), 0.f);
    float r3 = fmaxf(fmaf(a2[1].y, s, b0.w), 0.f);
    float r4 = fmaxf(fmaf(a2[2].x, s, b1.x), 0.f);
    float r5 = fmaxf(fmaf(a2[2].y, s, b1.y), 0.f);
    float r6 = fmaxf(fmaf(a2[3].x, s, b1.z), 0.f);
    float r7 = fmaxf(fmaf(a2[3].y, s, b1.w), 0.f);
    uint4 o;
    o.x = (uint)f2b(r0) | ((uint)f2b(r1) << 16);
    o.y = (uint)f2b(r2) | ((uint)f2b(r3) << 16);
    o.z = (uint)f2b(r4) | ((uint)f2b(r5) << 16);
    o.w = (uint)f2b(r6) | ((uint)f2b(r7) << 16);
    ((uint4*)h)[(size_t)node * 16 + q] = o;
  }
}

// ---------------- pooling (vectorized gather + pk_add): one wave per node ----------------
__global__ void pool_kernel(const ushort* __restrict__ zb, float* __restrict__ out,
                            const int* __restrict__ csr, const int* __restrict__ offsets,
                            const float* __restrict__ bo, int N) {
  int node = blockIdx.x * 4 + (threadIdx.x >> 6);
  if (node >= N) return;
  const int l = threadIdx.x & 63;
  const int g = l >> 3;
  const int p = l & 7;
  const uint4* zp = (const uint4*)zb;  // 8 uint4 per row
  int off = offsets[node], end = offsets[node + 1];
  f32x2 a2[4];
#pragma unroll
  for (int k = 0; k < 4; ++k) a2[k] = (f32x2)0.f;

  int i = off;
  for (; i + 16 <= end; i += 16) {
    int s0 = csr[i + g];
    int s1 = csr[i + 8 + g];
    uint4 v0 = zp[(size_t)s0 * 8 + p];
    uint4 v1 = zp[(size_t)s1 * 8 + p];
    ACCV(v0) ACCV(v1)
  }
  if (i + 8 <= end) {
    int s0 = csr[i + g];
    uint4 v0 = zp[(size_t)s0 * 8 + p];
    ACCV(v0)
    i += 8;
  }
  if (i < end) {
    bool valid = (i + g) < end;
    int s0 = csr[valid ? (i + g) : (end - 1)];
    uint4 v0 = zp[(size_t)s0 * 8 + p];
    if (valid) { ACCV(v0) }
  }
#pragma unroll
  for (int k = 0; k < 4; ++k) {
    a2[k].x += __shfl_xor(a2[k].x, 8);
    a2[k].y += __shfl_xor(a2[k].y, 8);
    a2[k].x += __shfl_xor(a2[k].x, 16);
    a2[k].y += __shfl_xor(a2[k].y, 16);
    a2[k].x += __shfl_xor(a2[k].x, 32);
    a2[k].y += __shfl_xor(a2[k].y, 32);
  }
  if (g == 0) {
    float4 o0, o1;
    o0.x = a2[0].x + bo[8 * p + 0];
    o0.y = a2[0].y + bo[8 * p + 1];
    o0.z = a2[1].x + bo[8 * p + 2];
    o0.w = a2[1].y + bo[8 * p + 3];
    o1.x = a2[2].x + bo[8 * p + 4];
    o1.y = a2[2].y + bo[8 * p + 5];
    o1.z = a2[3].x + bo[8 * p + 6];
    o1.w = a2[3].y + bo[8 * p + 7];
    float* op = out + (size_t)node * 64 + 8 * p;
    *(float4*)op = o0;
    *(float4*)(op + 4) = o1;
  }
}

extern "C" void kernel_launch(void* const* d_in, const int* in_sizes, int n_in,
                              void* d_out, int out_size, void* d_ws, size_t ws_size,
                              hipStream_t stream) {
  const float* feats = (const float*)d_in[0];
  const int* src = (const int*)d_in[1];
  const int* dst = (const int*)d_in[2];
  const float* W0 = (const float*)d_in[3];
  const float* b0 = (const float*)d_in[4];
  const float* W1 = (const float*)d_in[5];
  const float* b1 = (const float*)d_in[6];
  const float* W2 = (const float*)d_in[7];
  const float* b2 = (const float*)d_in[8];
  const float* Wo = (const float*)d_in[9];
  const float* bo = (const float*)d_in[10];
  float* out = (float*)d_out;

  const int N = in_sizes[0] / 128;
  const int E = in_sizes[1];
  const int NP = (N + 127) & ~127;
  const int NBK = (N + 255) >> SH;
  const int SCN = NBK * G1;
  const int SCN2 = 2 * SCN;

  char* p = (char*)d_ws;
  auto take = [&](size_t bytes) { char* q = p; p += (bytes + 255) & ~(size_t)255; return q; };
  ushort* xb   = (ushort*)take((size_t)NP * 128 * 2);  // feats bf16; becomes h3 after agg3
  char*  yregion = take((size_t)NP * 128 * 2);         // build temps -> y -> zbb
  ushort* ybuf = (ushort*)yregion;
  ushort* zbb  = (ushort*)yregion;
  uint*  ebuf  = (uint*)yregion;                       // E*4
  uchar* sbuf  = (uchar*)(yregion + (size_t)E * 4);    // E*1
  int*   H     = (int*)(yregion + (size_t)E * 5 + 256);// SCN2*4
  int*   H2    = H + SCN2;                             // SCN2*4
  ushort* h1   = (ushort*)take((size_t)NP * 128 * 2);
  ushort* h2   = (ushort*)take((size_t)NP * 128 * 2);
  ushort* h3   = xb;
  ushort* Wt1 = (ushort*)take((size_t)128 * 128 * 2);
  ushort* Wt2 = (ushort*)take((size_t)128 * 128 * 2);
  ushort* Wt3 = (ushort*)take((size_t)128 * 128 * 2);
  ushort* Wz  = (ushort*)take((size_t)64 * 384 * 2);
  float* out_norm = (float*)take((size_t)N * 4);
  float* in_norm  = (float*)take((size_t)N * 4);
  int* offsets    = (int*)take((size_t)(N + 1) * 4);
  int* blocksums  = (int*)take(1024);
  int* csr        = (int*)take((size_t)E * 4);
  (void)ws_size; (void)n_in; (void)out_size;

  // ---- graph build (no global atomics; temps live in yregion) ----
  p1hist<<<G1, 256, 0, stream>>>(src, dst, E, NBK, SCN, H);
  int NBs = (SCN2 + 2047) / 2048;
  scanA<<<NBs, 256, 0, stream>>>(H, SCN2, H2, blocksums);
  scanB<<<1, 256, 0, stream>>>(blocksums, NBs);
  scanC<<<512, 256, 0, stream>>>(H2, blocksums, SCN2);
  p1scatter<<<G1, 256, 0, stream>>>(src, dst, E, NBK, SCN, H2, ebuf, sbuf);
  p2build<<<NBK, 256, 0, stream>>>(ebuf, sbuf, H2, E, N, NBK, SCN,
                                   offsets, csr, out_norm, in_norm);

  // ---- dense prep ----
  prep_w<<<448, 64, 0, stream>>>(W0, W1, W2, Wo, Wt1, Wt2, Wt3, Wz);
  prep_x<<<1024, 256, 0, stream>>>(feats, (uint4*)xb, N * 16);

  dim3 blk(256);
  int rb = NP / 128;
  int ab = (N + 3) / 4;

  gemm_layer<<<rb, blk, 0, stream>>>(xb, N, Wt1, ybuf, out_norm);
  agg_kernel<<<ab, blk, 0, stream>>>(ybuf, (uint*)h1, csr, offsets, in_norm, b0, N);
  gemm_layer<<<rb, blk, 0, stream>>>(h1, N, Wt2, ybuf, out_norm);
  agg_kernel<<<ab, blk, 0, stream>>>(ybuf, (uint*)h2, csr, offsets, in_norm, b1, N);
  gemm_layer<<<rb, blk, 0, stream>>>(h2, N, Wt3, ybuf, out_norm);
  agg_kernel<<<ab, blk, 0, stream>>>(ybuf, (uint*)h3, csr, offsets, in_norm, b2, N);
  gemm_z<<<rb, blk, 0, stream>>>(h1, h2, h3, N, Wz, zbb);
  pool_kernel<<<ab, blk, 0, stream>>>(zbb, out, csr, offsets, bo, N);
}